// Round 6
// baseline (1866.222 us; speedup 1.0000x reference)
//
#include <hip/hip_runtime.h>

#define N_SRC 50000
#define N_DST 50000
#define N_EDGES 1600000
#define D_NEIGH 128
#define D_SELF 128
#define D_EDGE 32
#define D_OUT 256
#define K_TOT 288   // [0,128)=self(f32 src), [128,288)=hn(bf16 in hnb)
#define D_HN 160

#define BSH 6                       // 64 dst nodes per bucket
#define BNODES 64
#define NBUCK ((N_DST + BNODES - 1) / BNODES)   // 782
#define CPAD 16                     // pad counters to one per 64B line

typedef float f32x4 __attribute__((ext_vector_type(4)));
typedef short s16x8 __attribute__((ext_vector_type(8)));

__device__ __forceinline__ ushort f2bf(float x) {
    unsigned b = __float_as_uint(x);
    return (ushort)((b + 0x7fffu + ((b >> 16) & 1u)) >> 16);  // RNE
}
__device__ __forceinline__ float bflo(unsigned u) { return __uint_as_float(u << 16); }
__device__ __forceinline__ float bfhi(unsigned u) { return __uint_as_float(u & 0xffff0000u); }

// ---------------- h_neigh f32 -> bf16 (halves gather volume) ----------------

__global__ void k_cvt(const float* __restrict__ in, ushort* __restrict__ out, int n4) {
    int i = blockIdx.x * blockDim.x + threadIdx.x;
    if (i < n4) {
        float4 f = ((const float4*)in)[i];
        ((ushort4*)out)[i] = make_ushort4(f2bf(f.x), f2bf(f.y), f2bf(f.z), f2bf(f.w));
    }
}

// ---------------- bucket histogram (LDS-aggregated) ----------------

__global__ __launch_bounds__(256) void k_bcount(const int* __restrict__ dst,
                                                int* __restrict__ gcnt, int n) {
    __shared__ int h[NBUCK];
    for (int i = threadIdx.x; i < NBUCK; i += 256) h[i] = 0;
    __syncthreads();
    for (int i = blockIdx.x * 256 + threadIdx.x; i < n; i += gridDim.x * 256)
        atomicAdd(&h[dst[i] >> BSH], 1);
    __syncthreads();
    for (int i = threadIdx.x; i < NBUCK; i += 256)
        if (h[i]) atomicAdd(&gcnt[i * CPAD], h[i]);
}

// ---------------- bucket prefix scan (one block) ----------------

__global__ __launch_bounds__(1024) void k_bscan(const int* __restrict__ gcnt,
                                                int* __restrict__ gbase,
                                                int* __restrict__ gcur) {
    __shared__ int part[1024];
    const int t = threadIdx.x;
    const int v = (t < NBUCK) ? gcnt[t * CPAD] : 0;
    part[t] = v;
    __syncthreads();
    for (int off = 1; off < 1024; off <<= 1) {
        int p = (t >= off) ? part[t - off] : 0;
        __syncthreads();
        part[t] += p;
        __syncthreads();
    }
    if (t < NBUCK) {
        const int ex = part[t] - v;
        gbase[t] = ex;
        gcur[t * CPAD] = ex;
    }
    if (t == 1023) gbase[NBUCK] = part[1023];
}

// ---------------- bucketed scatter ----------------
// pk[p] = {edge id, src | dst_local<<16}. Writes land in per-bucket 16KB
// windows -> L2 merges lines before eviction (vs 8x line amplification of
// the old fully-random CSR scatter).

__global__ __launch_bounds__(256) void k_bscatter(const int* __restrict__ dst,
                                                  const int* __restrict__ src,
                                                  int* __restrict__ gcur,
                                                  int2* __restrict__ pk, int n) {
    int i = blockIdx.x * 256 + threadIdx.x;
    if (i < n) {
        const int d = dst[i];
        const int b = d >> BSH;
        const int p = atomicAdd(&gcur[b * CPAD], 1);
        pk[p] = make_int2(i, src[i] | ((d & (BNODES - 1)) << 16));
    }
}

// ---------------- bucketed aggregation ----------------
// One block (8 waves) per bucket of 64 dst nodes. 64x160 f32 accumulator in
// LDS (41KB -> 3 blocks/CU); edges accumulated via ds_add_f32 (no return).
// Degree counted in LDS as a side effect (kills the old k_deg pass).
// Bank math: acc row stride 160 f32 (== 0 mod 32 banks) -> h_neigh adds are
// 2 lanes/bank (free, m136); ef adds likewise.

__global__ __launch_bounds__(512) void k_bagg(const int* __restrict__ gbase,
                                              const int2* __restrict__ pk,
                                              const ushort* __restrict__ hb,
                                              const float* __restrict__ ef,
                                              ushort* __restrict__ hnb) {
    __shared__ float acc[BNODES][D_HN];
    __shared__ int ldeg[BNODES];
    const int tid = threadIdx.x;
    const int lane = tid & 63;
    const int wid = tid >> 6;

    for (int i = tid; i < BNODES * D_HN; i += 512) ((float*)acc)[i] = 0.f;
    if (tid < BNODES) ldeg[tid] = 0;
    __syncthreads();

    const int b = blockIdx.x;
    const int start = gbase[b];
    const int end = gbase[b + 1];
    const ushort* hbase = hb + 2 * lane;
    const float* ebase = ef + (lane & 31);
    const int g = lane >> 5;

    for (int c = start + wid * 64; c < end; c += 512) {
        const int rem = end - c;
        const int m = rem < 64 ? rem : 64;
        int e = 0, y = 0;
        if (lane < m) {
            const int2 p = pk[c + lane];
            e = p.x; y = p.y;
            atomicAdd(&ldeg[(y >> 16) & 63], 1);
        }
        int i = 0;
        for (; i + 8 <= m; i += 8) {
            unsigned u[8];
            int dl[8], dle[4];
            float te[4];
#pragma unroll
            for (int j = 0; j < 8; j++) {
                const int yy = __builtin_amdgcn_readlane(y, i + j);
                dl[j] = (yy >> 16) & 63;
                u[j] = *(const unsigned*)(hbase + (size_t)(yy & 0xFFFF) * D_NEIGH);
            }
#pragma unroll
            for (int j = 0; j < 4; j++) {
                const int ee = __shfl(e, i + 2 * j + g);
                const int ye = __shfl(y, i + 2 * j + g);
                dle[j] = (ye >> 16) & 63;
                te[j] = ebase[(size_t)ee * D_EDGE];
            }
#pragma unroll
            for (int j = 0; j < 8; j++) {
                unsafeAtomicAdd(&acc[dl[j]][2 * lane], bflo(u[j]));
                unsafeAtomicAdd(&acc[dl[j]][2 * lane + 1], bfhi(u[j]));
            }
#pragma unroll
            for (int j = 0; j < 4; j++)
                unsafeAtomicAdd(&acc[dle[j]][128 + (lane & 31)], te[j]);
        }
        for (; i < m; ++i) {
            const int yy = __builtin_amdgcn_readlane(y, i);
            const int ei = __builtin_amdgcn_readlane(e, i);
            const int dli = (yy >> 16) & 63;
            const unsigned uu = *(const unsigned*)(hbase + (size_t)(yy & 0xFFFF) * D_NEIGH);
            unsafeAtomicAdd(&acc[dli][2 * lane], bflo(uu));
            unsafeAtomicAdd(&acc[dli][2 * lane + 1], bfhi(uu));
            if (lane < D_EDGE) unsafeAtomicAdd(&acc[dli][128 + lane], ef[(size_t)ei * D_EDGE + lane]);
        }
    }
    __syncthreads();

    const int nbase = b << BSH;
    for (int idx = tid; idx < BNODES * D_HN; idx += 512) {
        const int nloc = idx / D_HN;
        const int dd = idx - nloc * D_HN;
        const int gn = nbase + nloc;
        if (gn < N_DST) {
            const int dg = ldeg[nloc];
            const float inv = dg > 0 ? 1.f / (float)dg : 1.f;
            hnb[(size_t)gn * D_HN + dd] = f2bf(acc[nloc][dd] * inv);
        }
    }
}

// ---------------- Fused bf16-MFMA GEMM + ReLU + row-L2-norm ----------------

__global__ __launch_bounds__(512) void k_gemm_norm(const float* __restrict__ h_self,
                                                   const ushort* __restrict__ hnb,
                                                   const float* __restrict__ Wself,
                                                   const float* __restrict__ Wneigh,
                                                   float* __restrict__ out) {
    __shared__ __align__(16) ushort Xs[64 * 40];
    __shared__ __align__(16) ushort Ws[256 * 40];
    __shared__ float rsum[4][64];
    __shared__ float invn[64];

    const int tid = threadIdx.x;
    const int lane = tid & 63;
    const int wid = tid >> 6;
    const int wm = wid >> 2;
    const int wn = wid & 3;
    const int brow = blockIdx.x * 64;

    const int xrow = tid >> 3, xpart = tid & 7;
    const int wcol = tid >> 1, whalf = tid & 1;

    f32x4 acc[2][4] = {};

    for (int k0 = 0; k0 < K_TOT; k0 += 32) {
        {
            const int gr = brow + xrow;
            ushort4 v = make_ushort4(0, 0, 0, 0);
            if (gr < N_DST) {
                if (k0 < 128) {
                    float4 f = *(const float4*)(h_self + (size_t)gr * D_SELF + k0 + xpart * 4);
                    v = make_ushort4(f2bf(f.x), f2bf(f.y), f2bf(f.z), f2bf(f.w));
                } else {
                    v = *(const ushort4*)(hnb + (size_t)gr * D_HN + (k0 - 128) + xpart * 4);
                }
            }
            *(ushort4*)&Xs[xrow * 40 + xpart * 4] = v;
        }
        {
            const int kb = k0 + whalf * 16;
            const float* wp;
            int kk;
            if (kb < 128) { wp = Wself + (size_t)wcol * D_SELF;  kk = kb; }
            else          { wp = Wneigh + (size_t)wcol * D_HN;   kk = kb - 128; }
            float4 f0 = *(const float4*)(wp + kk);
            float4 f1 = *(const float4*)(wp + kk + 4);
            float4 f2 = *(const float4*)(wp + kk + 8);
            float4 f3 = *(const float4*)(wp + kk + 12);
            ushort* wb = &Ws[wcol * 40 + whalf * 16];
            *(ushort4*)(wb + 0)  = make_ushort4(f2bf(f0.x), f2bf(f0.y), f2bf(f0.z), f2bf(f0.w));
            *(ushort4*)(wb + 4)  = make_ushort4(f2bf(f1.x), f2bf(f1.y), f2bf(f1.z), f2bf(f1.w));
            *(ushort4*)(wb + 8)  = make_ushort4(f2bf(f2.x), f2bf(f2.y), f2bf(f2.z), f2bf(f2.w));
            *(ushort4*)(wb + 12) = make_ushort4(f2bf(f3.x), f2bf(f3.y), f2bf(f3.z), f2bf(f3.w));
        }
        __syncthreads();

        s16x8 af[2], bf[4];
        const int koff = (lane >> 4) * 8;
        const int rsel = lane & 15;
#pragma unroll
        for (int fi = 0; fi < 2; fi++)
            af[fi] = *(const s16x8*)&Xs[(wm * 32 + fi * 16 + rsel) * 40 + koff];
#pragma unroll
        for (int fj = 0; fj < 4; fj++)
            bf[fj] = *(const s16x8*)&Ws[(wn * 64 + fj * 16 + rsel) * 40 + koff];
#pragma unroll
        for (int fi = 0; fi < 2; fi++)
#pragma unroll
            for (int fj = 0; fj < 4; fj++)
                acc[fi][fj] = __builtin_amdgcn_mfma_f32_16x16x32_bf16(af[fi], bf[fj], acc[fi][fj], 0, 0, 0);
        __syncthreads();
    }

    float ss[2][4];
#pragma unroll
    for (int fi = 0; fi < 2; fi++)
#pragma unroll
        for (int j = 0; j < 4; j++) {
            float s = 0.f;
#pragma unroll
            for (int fj = 0; fj < 4; fj++) {
                float z = fmaxf(acc[fi][fj][j], 0.f);
                acc[fi][fj][j] = z;
                s += z * z;
            }
            ss[fi][j] = s;
        }
#pragma unroll
    for (int m = 1; m < 16; m <<= 1)
#pragma unroll
        for (int fi = 0; fi < 2; fi++)
#pragma unroll
            for (int j = 0; j < 4; j++) ss[fi][j] += __shfl_xor(ss[fi][j], m);
    if ((lane & 15) == 0) {
        const int gg = lane >> 4;
#pragma unroll
        for (int fi = 0; fi < 2; fi++)
#pragma unroll
            for (int j = 0; j < 4; j++)
                rsum[wn][wm * 32 + fi * 16 + gg * 4 + j] = ss[fi][j];
    }
    __syncthreads();
    if (tid < 64) {
        float t = rsum[0][tid] + rsum[1][tid] + rsum[2][tid] + rsum[3][tid];
        invn[tid] = (t > 0.f) ? 1.f / sqrtf(t) : 1.f;
    }
    __syncthreads();

#pragma unroll
    for (int fi = 0; fi < 2; fi++)
#pragma unroll
        for (int j = 0; j < 4; j++) {
            const int rl = wm * 32 + fi * 16 + (lane >> 4) * 4 + j;
            const int row = brow + rl;
            if (row < N_DST) {
                const float iv = invn[rl];
#pragma unroll
                for (int fj = 0; fj < 4; fj++)
                    out[(size_t)row * D_OUT + wn * 64 + fj * 16 + (lane & 15)] = acc[fi][fj][j] * iv;
            }
        }
}

// ---------------- launch ----------------

extern "C" void kernel_launch(void* const* d_in, const int* in_sizes, int n_in,
                              void* d_out, int out_size, void* d_ws, size_t ws_size,
                              hipStream_t stream) {
    const float* h_neigh = (const float*)d_in[0];
    const float* h_self  = (const float*)d_in[1];
    const float* ef      = (const float*)d_in[2];
    const int*   src     = (const int*)d_in[3];
    const int*   dst     = (const int*)d_in[4];
    const float* Wself   = (const float*)d_in[5];
    const float* Wneigh  = (const float*)d_in[6];
    float* out = (float*)d_out;

    char* ws = (char*)d_ws;
    int*   gcnt  = (int*)(ws + 0);          // 782*16 ints (padded), 64KB reserved
    int*   gcur  = (int*)(ws + 65536);      // 782*16 ints (padded)
    int*   gbase = (int*)(ws + 131072);     // 783 ints
    int2*  pk    = (int2*)(ws + 262144);    // 1.6M int2 = 12.8MB, ends 13062144
    ushort* hb   = (ushort*)(ws + 13062144); // 50000x128 bf16, ends 25862144
    ushort* hnb  = (ushort*)(ws + 25862144); // 50000x160 bf16, ends 41862144 (<42.4MB proven floor)

    hipMemsetAsync(gcnt, 0, NBUCK * CPAD * sizeof(int), stream);
    k_cvt<<<(N_SRC * D_NEIGH / 4 + 255) / 256, 256, 0, stream>>>(h_neigh, hb, N_SRC * D_NEIGH / 4);
    k_bcount<<<512, 256, 0, stream>>>(dst, gcnt, N_EDGES);
    k_bscan<<<1, 1024, 0, stream>>>(gcnt, gbase, gcur);
    k_bscatter<<<(N_EDGES + 255) / 256, 256, 0, stream>>>(dst, src, gcur, pk, N_EDGES);
    k_bagg<<<NBUCK, 512, 0, stream>>>(gbase, pk, hb, ef, hnb);
    k_gemm_norm<<<(N_DST + 63) / 64, 512, 0, stream>>>(h_self, hnb, Wself, Wneigh, out);
}

// Round 7
// 210.543 us; speedup vs baseline: 8.8639x; 8.8639x over previous
//
#include <hip/hip_runtime.h>

#define N_SRC 50000
#define N_DST 50000
#define N_EDGES 1600000
#define D_NEIGH 128
#define D_SELF 128
#define D_EDGE 32
#define D_OUT 256
#define K_TOT 288   // [0,128)=self(f32), [128,288)=hn(bf16)
#define D_HN 160

#define NB 196      // coarse buckets of 256 dst nodes
#define CPAD 16     // one counter per 64B line
#define CHUNK 2048

typedef float f32x4 __attribute__((ext_vector_type(4)));
typedef short s16x8 __attribute__((ext_vector_type(8)));

__device__ __forceinline__ ushort f2bf(float x) {
    unsigned b = __float_as_uint(x);
    return (ushort)((b + 0x7fffu + ((b >> 16) & 1u)) >> 16);  // RNE
}
__device__ __forceinline__ float bflo(unsigned u) { return __uint_as_float(u << 16); }
__device__ __forceinline__ float bfhi(unsigned u) { return __uint_as_float(u & 0xffff0000u); }

// ---------------- h_neigh f32 -> bf16 ----------------

__global__ void k_cvt(const float* __restrict__ in, ushort* __restrict__ out, int n4) {
    int i = blockIdx.x * blockDim.x + threadIdx.x;
    if (i < n4) {
        float4 f = ((const float4*)in)[i];
        ((ushort4*)out)[i] = make_ushort4(f2bf(f.x), f2bf(f.y), f2bf(f.z), f2bf(f.w));
    }
}

// ---------------- coarse bucket count ----------------

__global__ __launch_bounds__(256) void k_cnt1(const int* __restrict__ dst,
                                              int* __restrict__ gcnt0, int n) {
    __shared__ int h[NB];
    for (int t = threadIdx.x; t < NB; t += 256) h[t] = 0;
    __syncthreads();
    for (int i = blockIdx.x * 256 + threadIdx.x; i < n; i += gridDim.x * 256)
        atomicAdd(&h[dst[i] >> 8], 1);
    __syncthreads();
    for (int t = threadIdx.x; t < NB; t += 256)
        if (h[t]) atomicAdd(&gcnt0[t * CPAD], h[t]);
}

// ---------------- coarse scan (1 block) ----------------

__global__ __launch_bounds__(256) void k_scan1(const int* __restrict__ gcnt0,
                                               int* __restrict__ wbase,
                                               int* __restrict__ gcur0,
                                               int* __restrict__ row_start) {
    __shared__ int part[256];
    const int t = threadIdx.x;
    const int v = (t < NB) ? gcnt0[t * CPAD] : 0;
    part[t] = v;
    __syncthreads();
    for (int off = 1; off < 256; off <<= 1) {
        int p = (t >= off) ? part[t - off] : 0;
        __syncthreads();
        part[t] += p;
        __syncthreads();
    }
    if (t < NB) {
        const int ex = part[t] - v;
        wbase[t] = ex;
        gcur0[t * CPAD] = ex;
    }
    if (t == 255) {
        wbase[NB] = part[255];
        row_start[N_DST] = part[255];
    }
}

// ---------------- pass A: LDS-staged radix scatter into bucket windows -------
// Entry y = src(16b) | dst_local(8b)<<16 | cb(8b)<<24 (cb stripped on copy-out).
// Staged sort-by-bucket in LDS, then coalesced burst copy: full 64B lines.

__global__ __launch_bounds__(256) void k_scat1(const int* __restrict__ dst,
                                               const int* __restrict__ src,
                                               int* __restrict__ gcur0,
                                               int2* __restrict__ pk1, int n) {
    __shared__ int hist[NB];
    __shared__ int lbase[NB];
    __shared__ int gbase[NB];
    __shared__ int2 stage[CHUNK];
    const int tid = threadIdx.x;
    for (int c0 = blockIdx.x * CHUNK; c0 < n; c0 += gridDim.x * CHUNK) {
        const int m = min(CHUNK, n - c0);
        for (int t = tid; t < NB; t += 256) hist[t] = 0;
        __syncthreads();
        int d8[8], s8[8];
#pragma unroll
        for (int j = 0; j < 8; j++) {
            const int i = c0 + j * 256 + tid;
            if (i < n) { d8[j] = dst[i]; s8[j] = src[i]; atomicAdd(&hist[d8[j] >> 8], 1); }
        }
        __syncthreads();
        if (tid == 0) {
            int ex = 0;
            for (int b = 0; b < NB; b++) { lbase[b] = ex; ex += hist[b]; }
        }
        __syncthreads();
        for (int t = tid; t < NB; t += 256)
            gbase[t] = hist[t] ? atomicAdd(&gcur0[t * CPAD], hist[t]) : 0;
        __syncthreads();
        for (int t = tid; t < NB; t += 256) hist[t] = lbase[t];
        __syncthreads();
#pragma unroll
        for (int j = 0; j < 8; j++) {
            const int i = c0 + j * 256 + tid;
            if (i < n) {
                const unsigned cb = (unsigned)d8[j] >> 8;
                const int p = atomicAdd(&hist[cb], 1);
                stage[p] = make_int2(i, (int)((unsigned)s8[j] |
                                              (((unsigned)d8[j] & 255u) << 16) | (cb << 24)));
            }
        }
        __syncthreads();
        for (int t = tid; t < m; t += 256) {
            int2 v = stage[t];
            const int cb = (v.y >> 24) & 255;
            v.y &= 0x00FFFFFF;
            pk1[gbase[cb] + (t - lbase[cb])] = v;
        }
        __syncthreads();
    }
}

// ---------------- pass B: per-bucket sort to per-dst CSR + row_start ---------

__global__ __launch_bounds__(1024) void k_scat2(const int* __restrict__ wbase,
                                                const int2* __restrict__ pk1,
                                                int2* __restrict__ pk2,
                                                int* __restrict__ row_start) {
    __shared__ int part[256];
    __shared__ int cur[256];
    const int b = blockIdx.x;
    const int s = wbase[b], e = wbase[b + 1];
    const int tid = threadIdx.x;
    if (tid < 256) part[tid] = 0;
    __syncthreads();
    for (int i = s + tid; i < e; i += 1024)
        atomicAdd(&part[(pk1[i].y >> 16) & 255], 1);
    __syncthreads();
    const int c0 = (tid < 256) ? part[tid] : 0;
    __syncthreads();
    for (int off = 1; off < 256; off <<= 1) {
        int v = 0;
        if (tid < 256 && tid >= off) v = part[tid - off];
        __syncthreads();
        if (tid < 256) part[tid] += v;
        __syncthreads();
    }
    if (tid < 256) {
        const int base = s + part[tid] - c0;   // exclusive
        cur[tid] = base;
        const int gn = b * 256 + tid;
        if (gn < N_DST) row_start[gn] = base;
    }
    __syncthreads();
    for (int i = s + tid; i < e; i += 1024) {
        int2 v = pk1[i];
        const int dl = (v.y >> 16) & 255;
        const int p = atomicAdd(&cur[dl], 1);
        pk2[p] = make_int2(v.x, v.y & 0xFFFF);
    }
}

// ---------------- fallback CSR path (R5, proven) ----------------

__global__ void k_deg(const int* __restrict__ dst, int* __restrict__ deg, int n) {
    int i = blockIdx.x * blockDim.x + threadIdx.x;
    if (i < n) atomicAdd(&deg[dst[i]], 1);
}

__global__ __launch_bounds__(1024) void k_scan(const int* __restrict__ deg,
                                               int* __restrict__ row_start,
                                               int* __restrict__ cursor) {
    __shared__ int part[1024];
    const int t = threadIdx.x;
    const int CH = (N_DST + 1023) / 1024;
    const int b = t * CH;
    int s = 0;
    for (int i = 0; i < CH; i++) { int idx = b + i; if (idx < N_DST) s += deg[idx]; }
    part[t] = s;
    __syncthreads();
    for (int off = 1; off < 1024; off <<= 1) {
        int v = (t >= off) ? part[t - off] : 0;
        __syncthreads();
        part[t] += v;
        __syncthreads();
    }
    int ex = (t == 0) ? 0 : part[t - 1];
    for (int i = 0; i < CH; i++) {
        int idx = b + i;
        if (idx < N_DST) { row_start[idx] = ex; cursor[idx] = ex; ex += deg[idx]; }
    }
    if (t == 1023) row_start[N_DST] = part[1023];
}

__global__ void k_fill(const int* __restrict__ dst, const int* __restrict__ src,
                       int* __restrict__ cursor, int2* __restrict__ pk, int n) {
    int i = blockIdx.x * blockDim.x + threadIdx.x;
    if (i < n) {
        int p = atomicAdd(&cursor[dst[i]], 1);
        pk[p] = make_int2(i, src[i]);
    }
}

// ---------------- Aggregation: one wave per dst node (register accumulate) --

__global__ __launch_bounds__(64) void k_agg(const int* __restrict__ row_start,
                                            const int2* __restrict__ pk,
                                            const ushort* __restrict__ hb,
                                            const float* __restrict__ ef,
                                            ushort* __restrict__ hnb) {
    const int d = blockIdx.x;
    const int lane = threadIdx.x;
    const int start = row_start[d];
    const int end = row_start[d + 1];
    const int deg = end - start;
    float ax = 0.f, ay = 0.f, ae = 0.f;
    const ushort* hbase = hb + 2 * lane;
    const float* ebase = ef + (lane & 31);
    const int g = lane >> 5;

    for (int c = start; c < end; c += 64) {
        const int rem = end - c;
        const int m = rem < 64 ? rem : 64;
        int e = 0, s = 0;
        if (lane < m) { int2 p = pk[c + lane]; e = p.x; s = p.y; }
        int i = 0;
        for (; i + 8 <= m; i += 8) {
            unsigned u[8];
            float te[4];
#pragma unroll
            for (int j = 0; j < 8; j++) {
                const int si = __builtin_amdgcn_readlane(s, i + j);
                u[j] = *(const unsigned*)(hbase + (size_t)si * D_NEIGH);
            }
#pragma unroll
            for (int j = 0; j < 4; j++) {
                const int ee = __shfl(e, i + 2 * j + g);
                te[j] = ebase[(size_t)ee * D_EDGE];
            }
#pragma unroll
            for (int j = 0; j < 8; j++) { ax += bflo(u[j]); ay += bfhi(u[j]); }
#pragma unroll
            for (int j = 0; j < 4; j++) ae += te[j];
        }
        for (; i < m; ++i) {
            const int si = __builtin_amdgcn_readlane(s, i);
            const int ei = __builtin_amdgcn_readlane(e, i);
            const unsigned uu = *(const unsigned*)(hbase + (size_t)si * D_NEIGH);
            ax += bflo(uu); ay += bfhi(uu);
            if (lane < D_EDGE) ae += ef[(size_t)ei * D_EDGE + lane];
        }
    }

    ae += __shfl_xor(ae, 32);

    const float inv = 1.0f / (float)(deg > 0 ? deg : 1);
    ushort* o = hnb + (size_t)d * D_HN;
    *(ushort2*)(o + 2 * lane) = make_ushort2(f2bf(ax * inv), f2bf(ay * inv));
    if (lane < D_EDGE) o[128 + lane] = f2bf(ae * inv);
}

// ---------------- Fused bf16-MFMA GEMM + ReLU + row-L2-norm ----------------

__global__ __launch_bounds__(512) void k_gemm_norm(const float* __restrict__ h_self,
                                                   const ushort* __restrict__ hnb,
                                                   const float* __restrict__ Wself,
                                                   const float* __restrict__ Wneigh,
                                                   float* __restrict__ out) {
    __shared__ __align__(16) ushort Xs[64 * 40];
    __shared__ __align__(16) ushort Ws[256 * 40];
    __shared__ float rsum[4][64];
    __shared__ float invn[64];

    const int tid = threadIdx.x;
    const int lane = tid & 63;
    const int wid = tid >> 6;
    const int wm = wid >> 2;
    const int wn = wid & 3;
    const int brow = blockIdx.x * 64;

    const int xrow = tid >> 3, xpart = tid & 7;
    const int wcol = tid >> 1, whalf = tid & 1;

    f32x4 acc[2][4] = {};

    for (int k0 = 0; k0 < K_TOT; k0 += 32) {
        {
            const int gr = brow + xrow;
            ushort4 v = make_ushort4(0, 0, 0, 0);
            if (gr < N_DST) {
                if (k0 < 128) {
                    float4 f = *(const float4*)(h_self + (size_t)gr * D_SELF + k0 + xpart * 4);
                    v = make_ushort4(f2bf(f.x), f2bf(f.y), f2bf(f.z), f2bf(f.w));
                } else {
                    v = *(const ushort4*)(hnb + (size_t)gr * D_HN + (k0 - 128) + xpart * 4);
                }
            }
            *(ushort4*)&Xs[xrow * 40 + xpart * 4] = v;
        }
        {
            const int kb = k0 + whalf * 16;
            const float* wp;
            int kk;
            if (kb < 128) { wp = Wself + (size_t)wcol * D_SELF;  kk = kb; }
            else          { wp = Wneigh + (size_t)wcol * D_HN;   kk = kb - 128; }
            float4 f0 = *(const float4*)(wp + kk);
            float4 f1 = *(const float4*)(wp + kk + 4);
            float4 f2 = *(const float4*)(wp + kk + 8);
            float4 f3 = *(const float4*)(wp + kk + 12);
            ushort* wb = &Ws[wcol * 40 + whalf * 16];
            *(ushort4*)(wb + 0)  = make_ushort4(f2bf(f0.x), f2bf(f0.y), f2bf(f0.z), f2bf(f0.w));
            *(ushort4*)(wb + 4)  = make_ushort4(f2bf(f1.x), f2bf(f1.y), f2bf(f1.z), f2bf(f1.w));
            *(ushort4*)(wb + 8)  = make_ushort4(f2bf(f2.x), f2bf(f2.y), f2bf(f2.z), f2bf(f2.w));
            *(ushort4*)(wb + 12) = make_ushort4(f2bf(f3.x), f2bf(f3.y), f2bf(f3.z), f2bf(f3.w));
        }
        __syncthreads();

        s16x8 af[2], bf[4];
        const int koff = (lane >> 4) * 8;
        const int rsel = lane & 15;
#pragma unroll
        for (int fi = 0; fi < 2; fi++)
            af[fi] = *(const s16x8*)&Xs[(wm * 32 + fi * 16 + rsel) * 40 + koff];
#pragma unroll
        for (int fj = 0; fj < 4; fj++)
            bf[fj] = *(const s16x8*)&Ws[(wn * 64 + fj * 16 + rsel) * 40 + koff];
#pragma unroll
        for (int fi = 0; fi < 2; fi++)
#pragma unroll
            for (int fj = 0; fj < 4; fj++)
                acc[fi][fj] = __builtin_amdgcn_mfma_f32_16x16x32_bf16(af[fi], bf[fj], acc[fi][fj], 0, 0, 0);
        __syncthreads();
    }

    float ss[2][4];
#pragma unroll
    for (int fi = 0; fi < 2; fi++)
#pragma unroll
        for (int j = 0; j < 4; j++) {
            float s = 0.f;
#pragma unroll
            for (int fj = 0; fj < 4; fj++) {
                float z = fmaxf(acc[fi][fj][j], 0.f);
                acc[fi][fj][j] = z;
                s += z * z;
            }
            ss[fi][j] = s;
        }
#pragma unroll
    for (int m = 1; m < 16; m <<= 1)
#pragma unroll
        for (int fi = 0; fi < 2; fi++)
#pragma unroll
            for (int j = 0; j < 4; j++) ss[fi][j] += __shfl_xor(ss[fi][j], m);
    if ((lane & 15) == 0) {
        const int gg = lane >> 4;
#pragma unroll
        for (int fi = 0; fi < 2; fi++)
#pragma unroll
            for (int j = 0; j < 4; j++)
                rsum[wn][wm * 32 + fi * 16 + gg * 4 + j] = ss[fi][j];
    }
    __syncthreads();
    if (tid < 64) {
        float t = rsum[0][tid] + rsum[1][tid] + rsum[2][tid] + rsum[3][tid];
        invn[tid] = (t > 0.f) ? 1.f / sqrtf(t) : 1.f;
    }
    __syncthreads();

#pragma unroll
    for (int fi = 0; fi < 2; fi++)
#pragma unroll
        for (int j = 0; j < 4; j++) {
            const int rl = wm * 32 + fi * 16 + (lane >> 4) * 4 + j;
            const int row = brow + rl;
            if (row < N_DST) {
                const float iv = invn[rl];
#pragma unroll
                for (int fj = 0; fj < 4; fj++)
                    out[(size_t)row * D_OUT + wn * 64 + fj * 16 + (lane & 15)] = acc[fi][fj][j] * iv;
            }
        }
}

// ---------------- launch ----------------

extern "C" void kernel_launch(void* const* d_in, const int* in_sizes, int n_in,
                              void* d_out, int out_size, void* d_ws, size_t ws_size,
                              hipStream_t stream) {
    const float* h_neigh = (const float*)d_in[0];
    const float* h_self  = (const float*)d_in[1];
    const float* ef      = (const float*)d_in[2];
    const int*   src     = (const int*)d_in[3];
    const int*   dst     = (const int*)d_in[4];
    const float* Wself   = (const float*)d_in[5];
    const float* Wneigh  = (const float*)d_in[6];
    float* out = (float*)d_out;

    char* ws = (char*)d_ws;
    const size_t need_new = 54662144ull;   // radix layout below

    if (ws_size >= need_new) {
        int*   gcnt0 = (int*)(ws + 0);          // NB*16 ints, reserve 16KB
        int*   gcur0 = (int*)(ws + 16384);
        int*   wbase = (int*)(ws + 32768);      // NB+1 ints
        int*   row_start = (int*)(ws + 36864);  // 50001 ints, ends 236868
        int2*  pk1 = (int2*)(ws + 262144);      // 12.8MB -> 13062144
        int2*  pk2 = (int2*)(ws + 13062144);    // 12.8MB -> 25862144
        ushort* hb  = (ushort*)(ws + 25862144); // 12.8MB -> 38662144
        ushort* hnb = (ushort*)(ws + 38662144); // 16MB   -> 54662144

        hipMemsetAsync(gcnt0, 0, NB * CPAD * sizeof(int), stream);
        k_cvt<<<(N_SRC * D_NEIGH / 4 + 255) / 256, 256, 0, stream>>>(h_neigh, hb, N_SRC * D_NEIGH / 4);
        k_cnt1<<<512, 256, 0, stream>>>(dst, gcnt0, N_EDGES);
        k_scan1<<<1, 256, 0, stream>>>(gcnt0, wbase, gcur0, row_start);
        k_scat1<<<256, 256, 0, stream>>>(dst, src, gcur0, pk1, N_EDGES);
        k_scat2<<<NB, 1024, 0, stream>>>(wbase, pk1, pk2, row_start);
        k_agg<<<N_DST, 64, 0, stream>>>(row_start, pk2, hb, ef, hnb);
        k_gemm_norm<<<(N_DST + 63) / 64, 512, 0, stream>>>(h_self, hnb, Wself, Wneigh, out);
    } else {
        // R5 fallback (proven ws floor 42.4MB)
        int* deg       = (int*)(ws + 0);
        int* row_start = (int*)(ws + 262144);
        int* cursor    = (int*)(ws + 524288);
        int2* pk       = (int2*)(ws + 786432);   // -> 13586432
        ushort* hb     = (ushort*)(ws + 13586432); // -> 26386432
        ushort* hnb    = (ushort*)(ws + 26386432); // -> 42386432

        hipMemsetAsync(deg, 0, N_DST * sizeof(int), stream);
        k_cvt<<<(N_SRC * D_NEIGH / 4 + 255) / 256, 256, 0, stream>>>(h_neigh, hb, N_SRC * D_NEIGH / 4);
        k_deg<<<(N_EDGES + 255) / 256, 256, 0, stream>>>(dst, deg, N_EDGES);
        k_scan<<<1, 1024, 0, stream>>>(deg, row_start, cursor);
        k_fill<<<(N_EDGES + 255) / 256, 256, 0, stream>>>(dst, src, cursor, pk, N_EDGES);
        k_agg<<<N_DST, 64, 0, stream>>>(row_start, pk, hb, ef, hnb);
        k_gemm_norm<<<(N_DST + 63) / 64, 512, 0, stream>>>(h_self, hnb, Wself, Wneigh, out);
    }
}

// Round 8
// 208.180 us; speedup vs baseline: 8.9645x; 1.0113x over previous
//
#include <hip/hip_runtime.h>

#define N_SRC 50000
#define N_DST 50000
#define N_EDGES 1600000
#define D_NEIGH 128
#define D_SELF 128
#define D_EDGE 32
#define D_OUT 256
#define K_TOT 288   // [0,128)=self(f32), [128,288)=hn(bf16)
#define D_HN 160

#define NB 196      // coarse buckets of 256 dst nodes
#define CPAD 16     // one counter per 64B line
#define CHUNK 2048

typedef float f32x4 __attribute__((ext_vector_type(4)));
typedef short s16x8 __attribute__((ext_vector_type(8)));

__device__ __forceinline__ ushort f2bf(float x) {
    unsigned b = __float_as_uint(x);
    return (ushort)((b + 0x7fffu + ((b >> 16) & 1u)) >> 16);  // RNE
}
__device__ __forceinline__ float bflo(unsigned u) { return __uint_as_float(u << 16); }
__device__ __forceinline__ float bfhi(unsigned u) { return __uint_as_float(u & 0xffff0000u); }

// ---------------- h_neigh f32 -> bf16 ----------------

__global__ void k_cvt(const float* __restrict__ in, ushort* __restrict__ out, int n4) {
    int i = blockIdx.x * blockDim.x + threadIdx.x;
    if (i < n4) {
        float4 f = ((const float4*)in)[i];
        ((ushort4*)out)[i] = make_ushort4(f2bf(f.x), f2bf(f.y), f2bf(f.z), f2bf(f.w));
    }
}

// ---------------- coarse bucket count ----------------

__global__ __launch_bounds__(256) void k_cnt1(const int* __restrict__ dst,
                                              int* __restrict__ gcnt0, int n) {
    __shared__ int h[NB];
    for (int t = threadIdx.x; t < NB; t += 256) h[t] = 0;
    __syncthreads();
    for (int i = blockIdx.x * 256 + threadIdx.x; i < n; i += gridDim.x * 256)
        atomicAdd(&h[dst[i] >> 8], 1);
    __syncthreads();
    for (int t = threadIdx.x; t < NB; t += 256)
        if (h[t]) atomicAdd(&gcnt0[t * CPAD], h[t]);
}

// ---------------- coarse scan (1 block) ----------------

__global__ __launch_bounds__(256) void k_scan1(const int* __restrict__ gcnt0,
                                               int* __restrict__ wbase,
                                               int* __restrict__ gcur0,
                                               int* __restrict__ row_start) {
    __shared__ int part[256];
    const int t = threadIdx.x;
    const int v = (t < NB) ? gcnt0[t * CPAD] : 0;
    part[t] = v;
    __syncthreads();
    for (int off = 1; off < 256; off <<= 1) {
        int p = (t >= off) ? part[t - off] : 0;
        __syncthreads();
        part[t] += p;
        __syncthreads();
    }
    if (t < NB) {
        const int ex = part[t] - v;
        wbase[t] = ex;
        gcur0[t * CPAD] = ex;
    }
    if (t == 255) {
        wbase[NB] = part[255];
        row_start[N_DST] = part[255];
    }
}

// ---------------- pass A: LDS-staged radix scatter into bucket windows -------

__global__ __launch_bounds__(256) void k_scat1(const int* __restrict__ dst,
                                               const int* __restrict__ src,
                                               int* __restrict__ gcur0,
                                               int2* __restrict__ pk1, int n) {
    __shared__ int hist[NB];
    __shared__ int lbase[NB];
    __shared__ int gbase[NB];
    __shared__ int2 stage[CHUNK];
    const int tid = threadIdx.x;
    for (int c0 = blockIdx.x * CHUNK; c0 < n; c0 += gridDim.x * CHUNK) {
        const int m = min(CHUNK, n - c0);
        for (int t = tid; t < NB; t += 256) hist[t] = 0;
        __syncthreads();
        int d8[8], s8[8];
#pragma unroll
        for (int j = 0; j < 8; j++) {
            const int i = c0 + j * 256 + tid;
            if (i < n) { d8[j] = dst[i]; s8[j] = src[i]; atomicAdd(&hist[d8[j] >> 8], 1); }
        }
        __syncthreads();
        if (tid == 0) {
            int ex = 0;
            for (int b = 0; b < NB; b++) { lbase[b] = ex; ex += hist[b]; }
        }
        __syncthreads();
        for (int t = tid; t < NB; t += 256)
            gbase[t] = hist[t] ? atomicAdd(&gcur0[t * CPAD], hist[t]) : 0;
        __syncthreads();
        for (int t = tid; t < NB; t += 256) hist[t] = lbase[t];
        __syncthreads();
#pragma unroll
        for (int j = 0; j < 8; j++) {
            const int i = c0 + j * 256 + tid;
            if (i < n) {
                const unsigned cb = (unsigned)d8[j] >> 8;
                const int p = atomicAdd(&hist[cb], 1);
                stage[p] = make_int2(i, (int)((unsigned)s8[j] |
                                              (((unsigned)d8[j] & 255u) << 16) | (cb << 24)));
            }
        }
        __syncthreads();
        for (int t = tid; t < m; t += 256) {
            int2 v = stage[t];
            const int cb = (v.y >> 24) & 255;
            v.y &= 0x00FFFFFF;
            pk1[gbase[cb] + (t - lbase[cb])] = v;
        }
        __syncthreads();
    }
}

// ---------------- pass B: per-bucket sort to per-dst CSR + row_start ---------

__global__ __launch_bounds__(1024) void k_scat2(const int* __restrict__ wbase,
                                                const int2* __restrict__ pk1,
                                                int2* __restrict__ pk2,
                                                int* __restrict__ row_start) {
    __shared__ int part[256];
    __shared__ int cur[256];
    const int b = blockIdx.x;
    const int s = wbase[b], e = wbase[b + 1];
    const int tid = threadIdx.x;
    if (tid < 256) part[tid] = 0;
    __syncthreads();
    for (int i = s + tid; i < e; i += 1024)
        atomicAdd(&part[(pk1[i].y >> 16) & 255], 1);
    __syncthreads();
    const int c0 = (tid < 256) ? part[tid] : 0;
    __syncthreads();
    for (int off = 1; off < 256; off <<= 1) {
        int v = 0;
        if (tid < 256 && tid >= off) v = part[tid - off];
        __syncthreads();
        if (tid < 256) part[tid] += v;
        __syncthreads();
    }
    if (tid < 256) {
        const int base = s + part[tid] - c0;   // exclusive
        cur[tid] = base;
        const int gn = b * 256 + tid;
        if (gn < N_DST) row_start[gn] = base;
    }
    __syncthreads();
    for (int i = s + tid; i < e; i += 1024) {
        int2 v = pk1[i];
        const int dl = (v.y >> 16) & 255;
        const int p = atomicAdd(&cur[dl], 1);
        pk2[p] = make_int2(v.x, v.y & 0xFFFF);
    }
}

// ---------------- fallback CSR path ----------------

__global__ void k_deg(const int* __restrict__ dst, int* __restrict__ deg, int n) {
    int i = blockIdx.x * blockDim.x + threadIdx.x;
    if (i < n) atomicAdd(&deg[dst[i]], 1);
}

__global__ __launch_bounds__(1024) void k_scan(const int* __restrict__ deg,
                                               int* __restrict__ row_start,
                                               int* __restrict__ cursor) {
    __shared__ int part[1024];
    const int t = threadIdx.x;
    const int CH = (N_DST + 1023) / 1024;
    const int b = t * CH;
    int s = 0;
    for (int i = 0; i < CH; i++) { int idx = b + i; if (idx < N_DST) s += deg[idx]; }
    part[t] = s;
    __syncthreads();
    for (int off = 1; off < 1024; off <<= 1) {
        int v = (t >= off) ? part[t - off] : 0;
        __syncthreads();
        part[t] += v;
        __syncthreads();
    }
    int ex = (t == 0) ? 0 : part[t - 1];
    for (int i = 0; i < CH; i++) {
        int idx = b + i;
        if (idx < N_DST) { row_start[idx] = ex; cursor[idx] = ex; ex += deg[idx]; }
    }
    if (t == 1023) row_start[N_DST] = part[1023];
}

__global__ void k_fill(const int* __restrict__ dst, const int* __restrict__ src,
                       int* __restrict__ cursor, int2* __restrict__ pk, int n) {
    int i = blockIdx.x * blockDim.x + threadIdx.x;
    if (i < n) {
        int p = atomicAdd(&cursor[dst[i]], 1);
        pk[p] = make_int2(i, src[i]);
    }
}

// ---------------- Aggregation: one wave per dst node ----------------
// Half-wave split gathers: lanes 0-31 read edge A's hb row (8B/lane over 32
// lanes = 256B), lanes 32-63 edge B -> one dwordx2 instr covers 2 edges.
// 16-edge unroll = 8 hb + 8 ef gathers in flight. Cross-half combine via
// shfl_xor(32) at the end. Lane ll (0..31) owns dims {4ll..4ll+3}.

__global__ __launch_bounds__(64) void k_agg(const int* __restrict__ row_start,
                                            const int2* __restrict__ pk,
                                            const ushort* __restrict__ hb,
                                            const float* __restrict__ ef,
                                            ushort* __restrict__ hnb) {
    const int d = blockIdx.x;
    const int lane = threadIdx.x;
    const int ll = lane & 31;
    const int g = lane >> 5;
    const int start = row_start[d];
    const int end = row_start[d + 1];
    const int deg = end - start;
    float a0 = 0.f, a1 = 0.f, a2 = 0.f, a3 = 0.f, ae = 0.f;
    const ushort* hbase = hb + 4 * ll;
    const float* ebase = ef + ll;

    for (int c = start; c < end; c += 64) {
        const int rem = end - c;
        const int m = rem < 64 ? rem : 64;
        int e = 0, s = 0;
        if (lane < m) { int2 p = pk[c + lane]; e = p.x; s = p.y; }
        int i = 0;
        for (; i + 16 <= m; i += 16) {
            uint2 u[8];
            float te[8];
#pragma unroll
            for (int j = 0; j < 8; j++) {
                const int sj = __shfl(s, i + 2 * j + g);
                u[j] = *(const uint2*)(hbase + (size_t)sj * D_NEIGH);
            }
#pragma unroll
            for (int j = 0; j < 8; j++) {
                const int ee = __shfl(e, i + 2 * j + g);
                te[j] = ebase[(size_t)ee * D_EDGE];
            }
#pragma unroll
            for (int j = 0; j < 8; j++) {
                a0 += bflo(u[j].x); a1 += bfhi(u[j].x);
                a2 += bflo(u[j].y); a3 += bfhi(u[j].y);
                ae += te[j];
            }
        }
        for (; i + 8 <= m; i += 8) {
            uint2 u[4];
            float te[4];
#pragma unroll
            for (int j = 0; j < 4; j++) {
                const int sj = __shfl(s, i + 2 * j + g);
                u[j] = *(const uint2*)(hbase + (size_t)sj * D_NEIGH);
            }
#pragma unroll
            for (int j = 0; j < 4; j++) {
                const int ee = __shfl(e, i + 2 * j + g);
                te[j] = ebase[(size_t)ee * D_EDGE];
            }
#pragma unroll
            for (int j = 0; j < 4; j++) {
                a0 += bflo(u[j].x); a1 += bfhi(u[j].x);
                a2 += bflo(u[j].y); a3 += bfhi(u[j].y);
                ae += te[j];
            }
        }
        for (; i < m; ++i) {   // tail singles: half-wave 0 only
            const int si = __builtin_amdgcn_readlane(s, i);
            const int ei = __builtin_amdgcn_readlane(e, i);
            if (g == 0) {
                const uint2 uu = *(const uint2*)(hbase + (size_t)si * D_NEIGH);
                a0 += bflo(uu.x); a1 += bfhi(uu.x);
                a2 += bflo(uu.y); a3 += bfhi(uu.y);
                ae += ebase[(size_t)ei * D_EDGE];
            }
        }
    }

    a0 += __shfl_xor(a0, 32); a1 += __shfl_xor(a1, 32);
    a2 += __shfl_xor(a2, 32); a3 += __shfl_xor(a3, 32);
    ae += __shfl_xor(ae, 32);

    if (lane < 32) {
        const float inv = 1.0f / (float)(deg > 0 ? deg : 1);
        ushort* o = hnb + (size_t)d * D_HN;
        *(ushort4*)(o + 4 * ll) = make_ushort4(f2bf(a0 * inv), f2bf(a1 * inv),
                                               f2bf(a2 * inv), f2bf(a3 * inv));
        o[128 + ll] = f2bf(ae * inv);
    }
}

// ---------------- Fused bf16-MFMA GEMM + ReLU + row-L2-norm ----------------
// Block = 128 rows x 256 cols, 512 threads (8 waves as 4x2: each wave
// 32 rows x 128 cols = 2x8 frags of 16x16 -> 16 MFMA per K-step).

#define GBM 128

__global__ __launch_bounds__(512, 1) void k_gemm_norm(const float* __restrict__ h_self,
                                                      const ushort* __restrict__ hnb,
                                                      const float* __restrict__ Wself,
                                                      const float* __restrict__ Wneigh,
                                                      float* __restrict__ out) {
    __shared__ __align__(16) ushort Xs[GBM * 40];
    __shared__ __align__(16) ushort Ws[256 * 40];
    __shared__ float rsum[2][GBM];
    __shared__ float invn[GBM];

    const int tid = threadIdx.x;
    const int lane = tid & 63;
    const int wid = tid >> 6;
    const int wm = wid >> 1;          // 0..3: row-group of 32
    const int wn = wid & 1;           // 0..1: col-group of 128
    const int brow = blockIdx.x * GBM;

    const int xrow = tid >> 2, xpart = tid & 3;    // X stage: 8 bf16 per thread
    const int wcol = tid >> 1, whalf = tid & 1;    // W stage: 16 bf16 per thread

    f32x4 acc[2][8] = {};

    for (int k0 = 0; k0 < K_TOT; k0 += 32) {
        {   // ---- X tile: 128 rows x 32 k (bf16) ----
            const int gr = brow + xrow;
            ushort4 v0 = make_ushort4(0, 0, 0, 0), v1 = v0;
            if (gr < N_DST) {
                if (k0 < 128) {
                    const float* sp = h_self + (size_t)gr * D_SELF + k0 + xpart * 8;
                    float4 f0 = *(const float4*)(sp);
                    float4 f1 = *(const float4*)(sp + 4);
                    v0 = make_ushort4(f2bf(f0.x), f2bf(f0.y), f2bf(f0.z), f2bf(f0.w));
                    v1 = make_ushort4(f2bf(f1.x), f2bf(f1.y), f2bf(f1.z), f2bf(f1.w));
                } else {
                    const ushort* sp = hnb + (size_t)gr * D_HN + (k0 - 128) + xpart * 8;
                    v0 = *(const ushort4*)(sp);
                    v1 = *(const ushort4*)(sp + 4);
                }
            }
            *(ushort4*)&Xs[xrow * 40 + xpart * 8] = v0;
            *(ushort4*)&Xs[xrow * 40 + xpart * 8 + 4] = v1;
        }
        {   // ---- W tile: 256 cols x 32 k ----
            const int kb = k0 + whalf * 16;
            const float* wp;
            int kk;
            if (kb < 128) { wp = Wself + (size_t)wcol * D_SELF;  kk = kb; }
            else          { wp = Wneigh + (size_t)wcol * D_HN;   kk = kb - 128; }
            float4 f0 = *(const float4*)(wp + kk);
            float4 f1 = *(const float4*)(wp + kk + 4);
            float4 f2 = *(const float4*)(wp + kk + 8);
            float4 f3 = *(const float4*)(wp + kk + 12);
            ushort* wb = &Ws[wcol * 40 + whalf * 16];
            *(ushort4*)(wb + 0)  = make_ushort4(f2bf(f0.x), f2bf(f0.y), f2bf(f0.z), f2bf(f0.w));
            *(ushort4*)(wb + 4)  = make_ushort4(f2bf(f1.x), f2bf(f1.y), f2bf(f1.z), f2bf(f1.w));
            *(ushort4*)(wb + 8)  = make_ushort4(f2bf(f2.x), f2bf(f2.y), f2bf(f2.z), f2bf(f2.w));
            *(ushort4*)(wb + 12) = make_ushort4(f2bf(f3.x), f2bf(f3.y), f2bf(f3.z), f2bf(f3.w));
        }
        __syncthreads();

        s16x8 af[2], bf[8];
        const int koff = (lane >> 4) * 8;
        const int rsel = lane & 15;
#pragma unroll
        for (int fi = 0; fi < 2; fi++)
            af[fi] = *(const s16x8*)&Xs[(wm * 32 + fi * 16 + rsel) * 40 + koff];
#pragma unroll
        for (int fj = 0; fj < 8; fj++)
            bf[fj] = *(const s16x8*)&Ws[(wn * 128 + fj * 16 + rsel) * 40 + koff];
#pragma unroll
        for (int fi = 0; fi < 2; fi++)
#pragma unroll
            for (int fj = 0; fj < 8; fj++)
                acc[fi][fj] = __builtin_amdgcn_mfma_f32_16x16x32_bf16(af[fi], bf[fj], acc[fi][fj], 0, 0, 0);
        __syncthreads();
    }

    // relu + row sum-of-squares (C/D: col=lane&15, row=(lane>>4)*4+reg)
    float ss[2][4];
#pragma unroll
    for (int fi = 0; fi < 2; fi++)
#pragma unroll
        for (int j = 0; j < 4; j++) {
            float s = 0.f;
#pragma unroll
            for (int fj = 0; fj < 8; fj++) {
                float z = fmaxf(acc[fi][fj][j], 0.f);
                acc[fi][fj][j] = z;
                s += z * z;
            }
            ss[fi][j] = s;
        }
#pragma unroll
    for (int m = 1; m < 16; m <<= 1)
#pragma unroll
        for (int fi = 0; fi < 2; fi++)
#pragma unroll
            for (int j = 0; j < 4; j++) ss[fi][j] += __shfl_xor(ss[fi][j], m);
    if ((lane & 15) == 0) {
        const int gg = lane >> 4;
#pragma unroll
        for (int fi = 0; fi < 2; fi++)
#pragma unroll
            for (int j = 0; j < 4; j++)
                rsum[wn][wm * 32 + fi * 16 + gg * 4 + j] = ss[fi][j];
    }
    __syncthreads();
    if (tid < GBM) {
        float t = rsum[0][tid] + rsum[1][tid];
        invn[tid] = (t > 0.f) ? 1.f / sqrtf(t) : 1.f;
    }
    __syncthreads();

#pragma unroll
    for (int fi = 0; fi < 2; fi++)
#pragma unroll
        for (int j = 0; j < 4; j++) {
            const int rl = wm * 32 + fi * 16 + (lane >> 4) * 4 + j;
            const int row = brow + rl;
            if (row < N_DST) {
                const float iv = invn[rl];
#pragma unroll
                for (int fj = 0; fj < 8; fj++)
                    out[(size_t)row * D_OUT + wn * 128 + fj * 16 + (lane & 15)] = acc[fi][fj][j] * iv;
            }
        }
}

// ---------------- launch ----------------

extern "C" void kernel_launch(void* const* d_in, const int* in_sizes, int n_in,
                              void* d_out, int out_size, void* d_ws, size_t ws_size,
                              hipStream_t stream) {
    const float* h_neigh = (const float*)d_in[0];
    const float* h_self  = (const float*)d_in[1];
    const float* ef      = (const float*)d_in[2];
    const int*   src     = (const int*)d_in[3];
    const int*   dst     = (const int*)d_in[4];
    const float* Wself   = (const float*)d_in[5];
    const float* Wneigh  = (const float*)d_in[6];
    float* out = (float*)d_out;

    char* ws = (char*)d_ws;
    const size_t need_new = 54662144ull;

    if (ws_size >= need_new) {
        int*   gcnt0 = (int*)(ws + 0);
        int*   gcur0 = (int*)(ws + 16384);
        int*   wbase = (int*)(ws + 32768);
        int*   row_start = (int*)(ws + 36864);
        int2*  pk1 = (int2*)(ws + 262144);
        int2*  pk2 = (int2*)(ws + 13062144);
        ushort* hb  = (ushort*)(ws + 25862144);
        ushort* hnb = (ushort*)(ws + 38662144);

        hipMemsetAsync(gcnt0, 0, NB * CPAD * sizeof(int), stream);
        k_cvt<<<(N_SRC * D_NEIGH / 4 + 255) / 256, 256, 0, stream>>>(h_neigh, hb, N_SRC * D_NEIGH / 4);
        k_cnt1<<<512, 256, 0, stream>>>(dst, gcnt0, N_EDGES);
        k_scan1<<<1, 256, 0, stream>>>(gcnt0, wbase, gcur0, row_start);
        k_scat1<<<256, 256, 0, stream>>>(dst, src, gcur0, pk1, N_EDGES);
        k_scat2<<<NB, 1024, 0, stream>>>(wbase, pk1, pk2, row_start);
        k_agg<<<N_DST, 64, 0, stream>>>(row_start, pk2, hb, ef, hnb);
        k_gemm_norm<<<(N_DST + GBM - 1) / GBM, 512, 0, stream>>>(h_self, hnb, Wself, Wneigh, out);
    } else {
        int* deg       = (int*)(ws + 0);
        int* row_start = (int*)(ws + 262144);
        int* cursor    = (int*)(ws + 524288);
        int2* pk       = (int2*)(ws + 786432);
        ushort* hb     = (ushort*)(ws + 13586432);
        ushort* hnb    = (ushort*)(ws + 26386432);

        hipMemsetAsync(deg, 0, N_DST * sizeof(int), stream);
        k_cvt<<<(N_SRC * D_NEIGH / 4 + 255) / 256, 256, 0, stream>>>(h_neigh, hb, N_SRC * D_NEIGH / 4);
        k_deg<<<(N_EDGES + 255) / 256, 256, 0, stream>>>(dst, deg, N_EDGES);
        k_scan<<<1, 1024, 0, stream>>>(deg, row_start, cursor);
        k_fill<<<(N_EDGES + 255) / 256, 256, 0, stream>>>(dst, src, cursor, pk, N_EDGES);
        k_agg<<<N_DST, 64, 0, stream>>>(row_start, pk, hb, ef, hnb);
        k_gemm_norm<<<(N_DST + GBM - 1) / GBM, 512, 0, stream>>>(h_self, hnb, Wself, Wneigh, out);
    }
}

// Round 9
// 200.059 us; speedup vs baseline: 9.3284x; 1.0406x over previous
//
#include <hip/hip_runtime.h>

#define N_SRC 50000
#define N_DST 50000
#define N_EDGES 1600000
#define D_NEIGH 128
#define D_SELF 128
#define D_EDGE 32
#define D_OUT 256
#define K_TOT 288   // [0,128)=self(f32), [128,288)=hn(bf16)
#define D_HN 160

#define NB 196      // coarse buckets of 256 dst nodes
#define CPAD 16     // one counter per 64B line
#define CHUNK 2048

typedef float f32x4 __attribute__((ext_vector_type(4)));
typedef short s16x8 __attribute__((ext_vector_type(8)));

__device__ __forceinline__ ushort f2bf(float x) {
    unsigned b = __float_as_uint(x);
    return (ushort)((b + 0x7fffu + ((b >> 16) & 1u)) >> 16);  // RNE
}
__device__ __forceinline__ float bflo(unsigned u) { return __uint_as_float(u << 16); }
__device__ __forceinline__ float bfhi(unsigned u) { return __uint_as_float(u & 0xffff0000u); }

// ---------------- h_neigh f32 -> bf16 ----------------

__global__ void k_cvt(const float* __restrict__ in, ushort* __restrict__ out, int n4) {
    int i = blockIdx.x * blockDim.x + threadIdx.x;
    if (i < n4) {
        float4 f = ((const float4*)in)[i];
        ((ushort4*)out)[i] = make_ushort4(f2bf(f.x), f2bf(f.y), f2bf(f.z), f2bf(f.w));
    }
}

// ---------------- W -> bf16 fragment layout ----------------
// Wb[t][koff8][c][8]: t = K-step (9), koff8 = (lane>>4) octet (4), c = out col
// (256), 8 consecutive bf16 of k. 147KB total -> L2-resident; GEMM reads MFMA
// B-fragments straight from global, no LDS for W.

__global__ void k_wcvt(const float* __restrict__ Wself, const float* __restrict__ Wneigh,
                       ushort* __restrict__ Wb) {
    const int q = blockIdx.x * 256 + threadIdx.x;
    if (q >= 9 * 4 * 256) return;
    const int t = q >> 10;
    const int r = q & 1023;
    const int k8 = r >> 8;
    const int c = r & 255;
    const int kb = t * 32 + k8 * 8;
    const float* p = (kb < 128) ? (Wself + (size_t)c * D_SELF + kb)
                                : (Wneigh + (size_t)c * D_HN + (kb - 128));
    float4 f0 = *(const float4*)(p);
    float4 f1 = *(const float4*)(p + 4);
    ushort* o = Wb + (size_t)q * 8;
    *(ushort4*)(o)     = make_ushort4(f2bf(f0.x), f2bf(f0.y), f2bf(f0.z), f2bf(f0.w));
    *(ushort4*)(o + 4) = make_ushort4(f2bf(f1.x), f2bf(f1.y), f2bf(f1.z), f2bf(f1.w));
}

// ---------------- coarse bucket count ----------------

__global__ __launch_bounds__(256) void k_cnt1(const int* __restrict__ dst,
                                              int* __restrict__ gcnt0, int n) {
    __shared__ int h[NB];
    for (int t = threadIdx.x; t < NB; t += 256) h[t] = 0;
    __syncthreads();
    for (int i = blockIdx.x * 256 + threadIdx.x; i < n; i += gridDim.x * 256)
        atomicAdd(&h[dst[i] >> 8], 1);
    __syncthreads();
    for (int t = threadIdx.x; t < NB; t += 256)
        if (h[t]) atomicAdd(&gcnt0[t * CPAD], h[t]);
}

// ---------------- coarse scan (1 block) ----------------

__global__ __launch_bounds__(256) void k_scan1(const int* __restrict__ gcnt0,
                                               int* __restrict__ wbase,
                                               int* __restrict__ gcur0,
                                               int* __restrict__ row_start) {
    __shared__ int part[256];
    const int t = threadIdx.x;
    const int v = (t < NB) ? gcnt0[t * CPAD] : 0;
    part[t] = v;
    __syncthreads();
    for (int off = 1; off < 256; off <<= 1) {
        int p = (t >= off) ? part[t - off] : 0;
        __syncthreads();
        part[t] += p;
        __syncthreads();
    }
    if (t < NB) {
        const int ex = part[t] - v;
        wbase[t] = ex;
        gcur0[t * CPAD] = ex;
    }
    if (t == 255) {
        wbase[NB] = part[255];
        row_start[N_DST] = part[255];
    }
}

// ---------------- pass A: LDS-staged radix scatter into bucket windows -------

__global__ __launch_bounds__(256) void k_scat1(const int* __restrict__ dst,
                                               const int* __restrict__ src,
                                               int* __restrict__ gcur0,
                                               int2* __restrict__ pk1, int n) {
    __shared__ int hist[NB];
    __shared__ int lbase[NB];
    __shared__ int gbase[NB];
    __shared__ int2 stage[CHUNK];
    const int tid = threadIdx.x;
    for (int c0 = blockIdx.x * CHUNK; c0 < n; c0 += gridDim.x * CHUNK) {
        const int m = min(CHUNK, n - c0);
        for (int t = tid; t < NB; t += 256) hist[t] = 0;
        __syncthreads();
        int d8[8], s8[8];
#pragma unroll
        for (int j = 0; j < 8; j++) {
            const int i = c0 + j * 256 + tid;
            if (i < n) { d8[j] = dst[i]; s8[j] = src[i]; atomicAdd(&hist[d8[j] >> 8], 1); }
        }
        __syncthreads();
        if (tid == 0) {
            int ex = 0;
            for (int b = 0; b < NB; b++) { lbase[b] = ex; ex += hist[b]; }
        }
        __syncthreads();
        for (int t = tid; t < NB; t += 256)
            gbase[t] = hist[t] ? atomicAdd(&gcur0[t * CPAD], hist[t]) : 0;
        __syncthreads();
        for (int t = tid; t < NB; t += 256) hist[t] = lbase[t];
        __syncthreads();
#pragma unroll
        for (int j = 0; j < 8; j++) {
            const int i = c0 + j * 256 + tid;
            if (i < n) {
                const unsigned cb = (unsigned)d8[j] >> 8;
                const int p = atomicAdd(&hist[cb], 1);
                stage[p] = make_int2(i, (int)((unsigned)s8[j] |
                                              (((unsigned)d8[j] & 255u) << 16) | (cb << 24)));
            }
        }
        __syncthreads();
        for (int t = tid; t < m; t += 256) {
            int2 v = stage[t];
            const int cb = (v.y >> 24) & 255;
            v.y &= 0x00FFFFFF;
            pk1[gbase[cb] + (t - lbase[cb])] = v;
        }
        __syncthreads();
    }
}

// ---------------- pass B: per-bucket sort to per-dst CSR + row_start ---------

__global__ __launch_bounds__(1024) void k_scat2(const int* __restrict__ wbase,
                                                const int2* __restrict__ pk1,
                                                int2* __restrict__ pk2,
                                                int* __restrict__ row_start) {
    __shared__ int part[256];
    __shared__ int cur[256];
    const int b = blockIdx.x;
    const int s = wbase[b], e = wbase[b + 1];
    const int tid = threadIdx.x;
    if (tid < 256) part[tid] = 0;
    __syncthreads();
    for (int i = s + tid; i < e; i += 1024)
        atomicAdd(&part[(pk1[i].y >> 16) & 255], 1);
    __syncthreads();
    const int c0 = (tid < 256) ? part[tid] : 0;
    __syncthreads();
    for (int off = 1; off < 256; off <<= 1) {
        int v = 0;
        if (tid < 256 && tid >= off) v = part[tid - off];
        __syncthreads();
        if (tid < 256) part[tid] += v;
        __syncthreads();
    }
    if (tid < 256) {
        const int base = s + part[tid] - c0;   // exclusive
        cur[tid] = base;
        const int gn = b * 256 + tid;
        if (gn < N_DST) row_start[gn] = base;
    }
    __syncthreads();
    for (int i = s + tid; i < e; i += 1024) {
        int2 v = pk1[i];
        const int dl = (v.y >> 16) & 255;
        const int p = atomicAdd(&cur[dl], 1);
        pk2[p] = make_int2(v.x, v.y & 0xFFFF);
    }
}

// ---------------- fallback CSR path ----------------

__global__ void k_deg(const int* __restrict__ dst, int* __restrict__ deg, int n) {
    int i = blockIdx.x * blockDim.x + threadIdx.x;
    if (i < n) atomicAdd(&deg[dst[i]], 1);
}

__global__ __launch_bounds__(1024) void k_scan(const int* __restrict__ deg,
                                               int* __restrict__ row_start,
                                               int* __restrict__ cursor) {
    __shared__ int part[1024];
    const int t = threadIdx.x;
    const int CH = (N_DST + 1023) / 1024;
    const int b = t * CH;
    int s = 0;
    for (int i = 0; i < CH; i++) { int idx = b + i; if (idx < N_DST) s += deg[idx]; }
    part[t] = s;
    __syncthreads();
    for (int off = 1; off < 1024; off <<= 1) {
        int v = (t >= off) ? part[t - off] : 0;
        __syncthreads();
        part[t] += v;
        __syncthreads();
    }
    int ex = (t == 0) ? 0 : part[t - 1];
    for (int i = 0; i < CH; i++) {
        int idx = b + i;
        if (idx < N_DST) { row_start[idx] = ex; cursor[idx] = ex; ex += deg[idx]; }
    }
    if (t == 1023) row_start[N_DST] = part[1023];
}

__global__ void k_fill(const int* __restrict__ dst, const int* __restrict__ src,
                       int* __restrict__ cursor, int2* __restrict__ pk, int n) {
    int i = blockIdx.x * blockDim.x + threadIdx.x;
    if (i < n) {
        int p = atomicAdd(&cursor[dst[i]], 1);
        pk[p] = make_int2(i, src[i]);
    }
}

// ---------------- Aggregation: one wave per dst node ----------------
// Half-wave split gathers (lanes 0-31 edge A, 32-63 edge B), 32-edge unroll
// -> 16 hb + 16 ef gathers in flight per wave.

__global__ __launch_bounds__(64) void k_agg(const int* __restrict__ row_start,
                                            const int2* __restrict__ pk,
                                            const ushort* __restrict__ hb,
                                            const float* __restrict__ ef,
                                            ushort* __restrict__ hnb) {
    const int d = blockIdx.x;
    const int lane = threadIdx.x;
    const int ll = lane & 31;
    const int g = lane >> 5;
    const int start = row_start[d];
    const int end = row_start[d + 1];
    const int deg = end - start;
    float a0 = 0.f, a1 = 0.f, a2 = 0.f, a3 = 0.f, ae = 0.f;
    const ushort* hbase = hb + 4 * ll;
    const float* ebase = ef + ll;

    for (int c = start; c < end; c += 64) {
        const int rem = end - c;
        const int m = rem < 64 ? rem : 64;
        int e = 0, s = 0;
        if (lane < m) { int2 p = pk[c + lane]; e = p.x; s = p.y; }
        int i = 0;
        for (; i + 32 <= m; i += 32) {
            uint2 u[16];
            float te[16];
#pragma unroll
            for (int j = 0; j < 16; j++) {
                const int sj = __shfl(s, i + 2 * j + g);
                u[j] = *(const uint2*)(hbase + (size_t)sj * D_NEIGH);
            }
#pragma unroll
            for (int j = 0; j < 16; j++) {
                const int ee = __shfl(e, i + 2 * j + g);
                te[j] = ebase[(size_t)ee * D_EDGE];
            }
#pragma unroll
            for (int j = 0; j < 16; j++) {
                a0 += bflo(u[j].x); a1 += bfhi(u[j].x);
                a2 += bflo(u[j].y); a3 += bfhi(u[j].y);
                ae += te[j];
            }
        }
        for (; i + 8 <= m; i += 8) {
            uint2 u[4];
            float te[4];
#pragma unroll
            for (int j = 0; j < 4; j++) {
                const int sj = __shfl(s, i + 2 * j + g);
                u[j] = *(const uint2*)(hbase + (size_t)sj * D_NEIGH);
            }
#pragma unroll
            for (int j = 0; j < 4; j++) {
                const int ee = __shfl(e, i + 2 * j + g);
                te[j] = ebase[(size_t)ee * D_EDGE];
            }
#pragma unroll
            for (int j = 0; j < 4; j++) {
                a0 += bflo(u[j].x); a1 += bfhi(u[j].x);
                a2 += bflo(u[j].y); a3 += bfhi(u[j].y);
                ae += te[j];
            }
        }
        for (; i < m; ++i) {   // tail singles: half-wave 0 only
            const int si = __builtin_amdgcn_readlane(s, i);
            const int ei = __builtin_amdgcn_readlane(e, i);
            if (g == 0) {
                const uint2 uu = *(const uint2*)(hbase + (size_t)si * D_NEIGH);
                a0 += bflo(uu.x); a1 += bfhi(uu.x);
                a2 += bflo(uu.y); a3 += bfhi(uu.y);
                ae += ebase[(size_t)ei * D_EDGE];
            }
        }
    }

    a0 += __shfl_xor(a0, 32); a1 += __shfl_xor(a1, 32);
    a2 += __shfl_xor(a2, 32); a3 += __shfl_xor(a3, 32);
    ae += __shfl_xor(ae, 32);

    if (lane < 32) {
        const float inv = 1.0f / (float)(deg > 0 ? deg : 1);
        ushort* o = hnb + (size_t)d * D_HN;
        *(ushort4*)(o + 4 * ll) = make_ushort4(f2bf(a0 * inv), f2bf(a1 * inv),
                                               f2bf(a2 * inv), f2bf(a3 * inv));
        o[128 + ll] = f2bf(ae * inv);
    }
}

// ---------------- Fused bf16-MFMA GEMM + ReLU + row-L2-norm ----------------
// 128 rows x 256 cols, 512 threads (8 waves 4x2). X: LDS double-buffered
// (one barrier per K-step). W: MFMA B-fragments read directly from L2-resident
// Wb (147KB), no LDS, no per-block W staging.

#define GBM 128

__global__ __launch_bounds__(512) void k_gemm_norm(const float* __restrict__ h_self,
                                                   const ushort* __restrict__ hnb,
                                                   const ushort* __restrict__ Wb,
                                                   float* __restrict__ out) {
    __shared__ __align__(16) ushort Xs[2][GBM * 40];
    __shared__ float rsum[2][GBM];
    __shared__ float invn[GBM];

    const int tid = threadIdx.x;
    const int lane = tid & 63;
    const int wid = tid >> 6;
    const int wm = wid >> 1;          // 0..3: row-group of 32
    const int wn = wid & 1;           // 0..1: col-group of 128
    const int brow = blockIdx.x * GBM;
    const int xrow = tid >> 2, xpart = tid & 3;   // stage: 8 bf16 per thread
    const int koff8 = lane >> 4, rsel = lane & 15;

    f32x4 acc[2][8] = {};

    // stage K-step t into buffer bufi
    auto stageX = [&](int t, int bufi) {
        const int k0 = t * 32;
        const int gr = brow + xrow;
        ushort4 v0 = make_ushort4(0, 0, 0, 0), v1 = v0;
        if (gr < N_DST) {
            if (k0 < 128) {
                const float* sp = h_self + (size_t)gr * D_SELF + k0 + xpart * 8;
                float4 f0 = *(const float4*)(sp);
                float4 f1 = *(const float4*)(sp + 4);
                v0 = make_ushort4(f2bf(f0.x), f2bf(f0.y), f2bf(f0.z), f2bf(f0.w));
                v1 = make_ushort4(f2bf(f1.x), f2bf(f1.y), f2bf(f1.z), f2bf(f1.w));
            } else {
                const ushort* sp = hnb + (size_t)gr * D_HN + (k0 - 128) + xpart * 8;
                v0 = *(const ushort4*)(sp);
                v1 = *(const ushort4*)(sp + 4);
            }
        }
        *(ushort4*)&Xs[bufi][xrow * 40 + xpart * 8] = v0;
        *(ushort4*)&Xs[bufi][xrow * 40 + xpart * 8 + 4] = v1;
    };

    stageX(0, 0);
    __syncthreads();

    for (int t = 0; t < 9; t++) {
        if (t < 8) stageX(t + 1, (t + 1) & 1);
        s16x8 af[2], bf[8];
#pragma unroll
        for (int fi = 0; fi < 2; fi++)
            af[fi] = *(const s16x8*)&Xs[t & 1][(wm * 32 + fi * 16 + rsel) * 40 + koff8 * 8];
#pragma unroll
        for (int fj = 0; fj < 8; fj++)
            bf[fj] = *(const s16x8*)&Wb[((size_t)(t * 4 + koff8) * 256 +
                                         (wn * 128 + fj * 16 + rsel)) * 8];
#pragma unroll
        for (int fi = 0; fi < 2; fi++)
#pragma unroll
            for (int fj = 0; fj < 8; fj++)
                acc[fi][fj] = __builtin_amdgcn_mfma_f32_16x16x32_bf16(af[fi], bf[fj], acc[fi][fj], 0, 0, 0);
        __syncthreads();
    }

    // relu + row sum-of-squares (C/D: col=lane&15, row=(lane>>4)*4+reg)
    float ss[2][4];
#pragma unroll
    for (int fi = 0; fi < 2; fi++)
#pragma unroll
        for (int j = 0; j < 4; j++) {
            float s = 0.f;
#pragma unroll
            for (int fj = 0; fj < 8; fj++) {
                float z = fmaxf(acc[fi][fj][j], 0.f);
                acc[fi][fj][j] = z;
                s += z * z;
            }
            ss[fi][j] = s;
        }
#pragma unroll
    for (int m = 1; m < 16; m <<= 1)
#pragma unroll
        for (int fi = 0; fi < 2; fi++)
#pragma unroll
            for (int j = 0; j < 4; j++) ss[fi][j] += __shfl_xor(ss[fi][j], m);
    if ((lane & 15) == 0) {
        const int gg = lane >> 4;
#pragma unroll
        for (int fi = 0; fi < 2; fi++)
#pragma unroll
            for (int j = 0; j < 4; j++)
                rsum[wn][wm * 32 + fi * 16 + gg * 4 + j] = ss[fi][j];
    }
    __syncthreads();
    if (tid < GBM) {
        float t = rsum[0][tid] + rsum[1][tid];
        invn[tid] = (t > 0.f) ? 1.f / sqrtf(t) : 1.f;
    }
    __syncthreads();

#pragma unroll
    for (int fi = 0; fi < 2; fi++)
#pragma unroll
        for (int j = 0; j < 4; j++) {
            const int rl = wm * 32 + fi * 16 + (lane >> 4) * 4 + j;
            const int row = brow + rl;
            if (row < N_DST) {
                const float iv = invn[rl];
#pragma unroll
                for (int fj = 0; fj < 8; fj++)
                    out[(size_t)row * D_OUT + wn * 128 + fj * 16 + (lane & 15)] = acc[fi][fj][j] * iv;
            }
        }
}

// ---------------- launch ----------------

extern "C" void kernel_launch(void* const* d_in, const int* in_sizes, int n_in,
                              void* d_out, int out_size, void* d_ws, size_t ws_size,
                              hipStream_t stream) {
    const float* h_neigh = (const float*)d_in[0];
    const float* h_self  = (const float*)d_in[1];
    const float* ef      = (const float*)d_in[2];
    const int*   src     = (const int*)d_in[3];
    const int*   dst     = (const int*)d_in[4];
    const float* Wself   = (const float*)d_in[5];
    const float* Wneigh  = (const float*)d_in[6];
    float* out = (float*)d_out;

    char* ws = (char*)d_ws;
    const size_t need_new = 54662144ull + 147456ull;

    if (ws_size >= need_new) {
        int*   gcnt0 = (int*)(ws + 0);
        int*   gcur0 = (int*)(ws + 16384);
        int*   wbase = (int*)(ws + 32768);
        int*   row_start = (int*)(ws + 36864);
        int2*  pk1 = (int2*)(ws + 262144);
        int2*  pk2 = (int2*)(ws + 13062144);
        ushort* hb  = (ushort*)(ws + 25862144);
        ushort* hnb = (ushort*)(ws + 38662144);
        ushort* Wb  = (ushort*)(ws + 54662144);   // 147456B

        hipMemsetAsync(gcnt0, 0, NB * CPAD * sizeof(int), stream);
        k_cvt<<<(N_SRC * D_NEIGH / 4 + 255) / 256, 256, 0, stream>>>(h_neigh, hb, N_SRC * D_NEIGH / 4);
        k_wcvt<<<36, 256, 0, stream>>>(Wself, Wneigh, Wb);
        k_cnt1<<<512, 256, 0, stream>>>(dst, gcnt0, N_EDGES);
        k_scan1<<<1, 256, 0, stream>>>(gcnt0, wbase, gcur0, row_start);
        k_scat1<<<256, 256, 0, stream>>>(dst, src, gcur0, pk1, N_EDGES);
        k_scat2<<<NB, 1024, 0, stream>>>(wbase, pk1, pk2, row_start);
        k_agg<<<N_DST, 64, 0, stream>>>(row_start, pk2, hb, ef, hnb);
        k_gemm_norm<<<(N_DST + GBM - 1) / GBM, 512, 0, stream>>>(h_self, hnb, Wb, out);
    } else {
        int* deg       = (int*)(ws + 0);
        int* row_start = (int*)(ws + 262144);
        int* cursor    = (int*)(ws + 524288);
        int2* pk       = (int2*)(ws + 786432);
        ushort* hb     = (ushort*)(ws + 13586432);
        ushort* hnb    = (ushort*)(ws + 26386432);
        ushort* Wb     = (ushort*)(ws + 42386432);

        hipMemsetAsync(deg, 0, N_DST * sizeof(int), stream);
        k_cvt<<<(N_SRC * D_NEIGH / 4 + 255) / 256, 256, 0, stream>>>(h_neigh, hb, N_SRC * D_NEIGH / 4);
        k_wcvt<<<36, 256, 0, stream>>>(Wself, Wneigh, Wb);
        k_deg<<<(N_EDGES + 255) / 256, 256, 0, stream>>>(dst, deg, N_EDGES);
        k_scan<<<1, 1024, 0, stream>>>(deg, row_start, cursor);
        k_fill<<<(N_EDGES + 255) / 256, 256, 0, stream>>>(dst, src, cursor, pk, N_EDGES);
        k_agg<<<N_DST, 64, 0, stream>>>(row_start, pk, hb, ef, hnb);
        k_gemm_norm<<<(N_DST + GBM - 1) / GBM, 512, 0, stream>>>(h_self, hnb, Wb, out);
    }
}

// Round 10
// 172.160 us; speedup vs baseline: 10.8400x; 1.1620x over previous
//
#include <hip/hip_runtime.h>

#define N_SRC 50000
#define N_DST 50000
#define N_EDGES 1600000
#define D_NEIGH 128
#define D_SELF 128
#define D_EDGE 32
#define D_OUT 256
#define K_TOT 288   // [0,128)=self(f32), [128,288)=hn(bf16)
#define D_HN 160

#define NB 196      // coarse buckets of 256 dst nodes
#define CPAD 16     // one counter per 64B line
#define CHUNK 2048
#define CAPSH 14    // 16384-entry padded window per bucket (mean 8192, sigma 90)

typedef float f32x4 __attribute__((ext_vector_type(4)));
typedef short s16x8 __attribute__((ext_vector_type(8)));

__device__ __forceinline__ ushort f2bf(float x) {
    unsigned b = __float_as_uint(x);
    return (ushort)((b + 0x7fffu + ((b >> 16) & 1u)) >> 16);  // RNE
}
__device__ __forceinline__ float bflo(unsigned u) { return __uint_as_float(u << 16); }
__device__ __forceinline__ float bfhi(unsigned u) { return __uint_as_float(u & 0xffff0000u); }

// ---------------- fused pre-convert: h_neigh->bf16 + W->fragment bf16 -------
// blocks [0,6250): hb cvt. blocks [6250,6286): Wb cvt.
// Wb[t][koff8][c][8]: B-fragments read straight from L2 in GEMM.

__global__ void k_cvtall(const float* __restrict__ in, ushort* __restrict__ hb,
                         const float* __restrict__ Wself, const float* __restrict__ Wneigh,
                         ushort* __restrict__ Wb) {
    const int b = blockIdx.x;
    if (b < 6250) {
        const int i = b * 256 + threadIdx.x;   // 6.4M/4 groups
        float4 f = ((const float4*)in)[i];
        ((ushort4*)hb)[i] = make_ushort4(f2bf(f.x), f2bf(f.y), f2bf(f.z), f2bf(f.w));
    } else {
        const int q = (b - 6250) * 256 + threadIdx.x;
        if (q >= 9 * 4 * 256) return;
        const int t = q >> 10;
        const int r = q & 1023;
        const int k8 = r >> 8;
        const int c = r & 255;
        const int kb = t * 32 + k8 * 8;
        const float* p = (kb < 128) ? (Wself + (size_t)c * D_SELF + kb)
                                    : (Wneigh + (size_t)c * D_HN + (kb - 128));
        float4 f0 = *(const float4*)(p);
        float4 f1 = *(const float4*)(p + 4);
        ushort* o = Wb + (size_t)q * 8;
        *(ushort4*)(o)     = make_ushort4(f2bf(f0.x), f2bf(f0.y), f2bf(f0.z), f2bf(f0.w));
        *(ushort4*)(o + 4) = make_ushort4(f2bf(f1.x), f2bf(f1.y), f2bf(f1.z), f2bf(f1.w));
    }
}

// ---------------- pass A: LDS-staged radix scatter into PADDED windows -------
// No count/scan pre-passes: bucket b owns pk1[b<<CAPSH ..]; gcur0 (zeroed)
// tracks fill. Entry y = src | dst_local<<16 | cb<<24 (cb stripped on out).

__global__ __launch_bounds__(256) void k_scat1(const int* __restrict__ dst,
                                               const int* __restrict__ src,
                                               int* __restrict__ gcur0,
                                               int2* __restrict__ pk1, int n) {
    __shared__ int hist[NB];
    __shared__ int lbase[NB];
    __shared__ int gbase[NB];
    __shared__ int2 stage[CHUNK];
    const int tid = threadIdx.x;
    for (int c0 = blockIdx.x * CHUNK; c0 < n; c0 += gridDim.x * CHUNK) {
        const int m = min(CHUNK, n - c0);
        for (int t = tid; t < NB; t += 256) hist[t] = 0;
        __syncthreads();
        int d8[8], s8[8];
#pragma unroll
        for (int j = 0; j < 8; j++) {
            const int i = c0 + j * 256 + tid;
            if (i < n) { d8[j] = dst[i]; s8[j] = src[i]; atomicAdd(&hist[d8[j] >> 8], 1); }
        }
        __syncthreads();
        if (tid == 0) {
            int ex = 0;
            for (int b = 0; b < NB; b++) { lbase[b] = ex; ex += hist[b]; }
        }
        __syncthreads();
        for (int t = tid; t < NB; t += 256)
            gbase[t] = hist[t] ? atomicAdd(&gcur0[t * CPAD], hist[t]) : 0;
        __syncthreads();
        for (int t = tid; t < NB; t += 256) hist[t] = lbase[t];
        __syncthreads();
#pragma unroll
        for (int j = 0; j < 8; j++) {
            const int i = c0 + j * 256 + tid;
            if (i < n) {
                const unsigned cb = (unsigned)d8[j] >> 8;
                const int p = atomicAdd(&hist[cb], 1);
                stage[p] = make_int2(i, (int)((unsigned)s8[j] |
                                              (((unsigned)d8[j] & 255u) << 16) | (cb << 24)));
            }
        }
        __syncthreads();
        for (int t = tid; t < m; t += 256) {
            int2 v = stage[t];
            const int cb = (v.y >> 24) & 255;
            v.y &= 0x00FFFFFF;
            pk1[((size_t)cb << CAPSH) + gbase[cb] + (t - lbase[cb])] = v;
        }
        __syncthreads();
    }
}

// ---------------- pass B: per-bucket sort -> per-dst runs + rs2(start,end) ---

__global__ __launch_bounds__(1024) void k_scat2(const int* __restrict__ gcur0,
                                                const int2* __restrict__ pk1,
                                                int2* __restrict__ pk2,
                                                int2* __restrict__ rs2) {
    __shared__ int part[256];
    __shared__ int cur[256];
    const int b = blockIdx.x;
    const int n = gcur0[b * CPAD];
    const int base = b << CAPSH;
    const int tid = threadIdx.x;
    if (tid < 256) part[tid] = 0;
    __syncthreads();
    for (int i = tid; i < n; i += 1024)
        atomicAdd(&part[(pk1[base + i].y >> 16) & 255], 1);
    __syncthreads();
    const int c0 = (tid < 256) ? part[tid] : 0;
    __syncthreads();
    for (int off = 1; off < 256; off <<= 1) {
        int v = 0;
        if (tid < 256 && tid >= off) v = part[tid - off];
        __syncthreads();
        if (tid < 256) part[tid] += v;
        __syncthreads();
    }
    if (tid < 256) {
        const int pfx = part[tid] - c0;   // exclusive
        cur[tid] = pfx;
        const int gn = b * 256 + tid;
        if (gn < N_DST) rs2[gn] = make_int2(base + pfx, base + pfx + c0);
    }
    __syncthreads();
    for (int i = tid; i < n; i += 1024) {
        int2 v = pk1[base + i];
        const int dl = (v.y >> 16) & 255;
        const int p = atomicAdd(&cur[dl], 1);
        pk2[base + p] = make_int2(v.x, v.y & 0xFFFF);
    }
}

// ---------------- fallback CSR path (small ws) ----------------

__global__ void k_deg(const int* __restrict__ dst, int* __restrict__ deg, int n) {
    int i = blockIdx.x * blockDim.x + threadIdx.x;
    if (i < n) atomicAdd(&deg[dst[i]], 1);
}

__global__ __launch_bounds__(1024) void k_scan(const int* __restrict__ deg,
                                               int* __restrict__ row_start,
                                               int* __restrict__ cursor) {
    __shared__ int part[1024];
    const int t = threadIdx.x;
    const int CH = (N_DST + 1023) / 1024;
    const int b = t * CH;
    int s = 0;
    for (int i = 0; i < CH; i++) { int idx = b + i; if (idx < N_DST) s += deg[idx]; }
    part[t] = s;
    __syncthreads();
    for (int off = 1; off < 1024; off <<= 1) {
        int v = (t >= off) ? part[t - off] : 0;
        __syncthreads();
        part[t] += v;
        __syncthreads();
    }
    int ex = (t == 0) ? 0 : part[t - 1];
    for (int i = 0; i < CH; i++) {
        int idx = b + i;
        if (idx < N_DST) { row_start[idx] = ex; cursor[idx] = ex; ex += deg[idx]; }
    }
    if (t == 1023) row_start[N_DST] = part[1023];
}

__global__ void k_fill(const int* __restrict__ dst, const int* __restrict__ src,
                       int* __restrict__ cursor, int2* __restrict__ pk, int n) {
    int i = blockIdx.x * blockDim.x + threadIdx.x;
    if (i < n) {
        int p = atomicAdd(&cursor[dst[i]], 1);
        pk[p] = make_int2(i, src[i]);
    }
}

__global__ void k_mkrs2(const int* __restrict__ row_start, int2* __restrict__ rs2) {
    int i = blockIdx.x * blockDim.x + threadIdx.x;
    if (i < N_DST) rs2[i] = make_int2(row_start[i], row_start[i + 1]);
}

// ---------------- Aggregation: one wave per dst node ----------------
// Half-wave split gathers (lanes 0-31 edge A, 32-63 edge B). ef loads are
// NON-TEMPORAL: the 205MB zero-reuse stream must not evict the 12.8MB hb
// working set from L2/L3 (hb re-read volume is 410MB of cache traffic).

__global__ __launch_bounds__(64) void k_agg(const int2* __restrict__ rs2,
                                            const int2* __restrict__ pk,
                                            const ushort* __restrict__ hb,
                                            const float* __restrict__ ef,
                                            ushort* __restrict__ hnb) {
    const int d = blockIdx.x;
    const int lane = threadIdx.x;
    const int ll = lane & 31;
    const int g = lane >> 5;
    const int2 se = rs2[d];
    const int start = se.x, end = se.y;
    const int deg = end - start;
    float a0 = 0.f, a1 = 0.f, a2 = 0.f, a3 = 0.f, ae = 0.f;
    const ushort* hbase = hb + 4 * ll;
    const float* ebase = ef + ll;

    for (int c = start; c < end; c += 64) {
        const int rem = end - c;
        const int m = rem < 64 ? rem : 64;
        int e = 0, s = 0;
        if (lane < m) { int2 p = pk[c + lane]; e = p.x; s = p.y; }
        int i = 0;
        for (; i + 16 <= m; i += 16) {
            uint2 u[8];
            float te[8];
#pragma unroll
            for (int j = 0; j < 8; j++) {
                const int sj = __shfl(s, i + 2 * j + g);
                u[j] = *(const uint2*)(hbase + (size_t)sj * D_NEIGH);
            }
#pragma unroll
            for (int j = 0; j < 8; j++) {
                const int ee = __shfl(e, i + 2 * j + g);
                te[j] = __builtin_nontemporal_load(ebase + (size_t)ee * D_EDGE);
            }
#pragma unroll
            for (int j = 0; j < 8; j++) {
                a0 += bflo(u[j].x); a1 += bfhi(u[j].x);
                a2 += bflo(u[j].y); a3 += bfhi(u[j].y);
                ae += te[j];
            }
        }
        for (; i + 8 <= m; i += 8) {
            uint2 u[4];
            float te[4];
#pragma unroll
            for (int j = 0; j < 4; j++) {
                const int sj = __shfl(s, i + 2 * j + g);
                u[j] = *(const uint2*)(hbase + (size_t)sj * D_NEIGH);
            }
#pragma unroll
            for (int j = 0; j < 4; j++) {
                const int ee = __shfl(e, i + 2 * j + g);
                te[j] = __builtin_nontemporal_load(ebase + (size_t)ee * D_EDGE);
            }
#pragma unroll
            for (int j = 0; j < 4; j++) {
                a0 += bflo(u[j].x); a1 += bfhi(u[j].x);
                a2 += bflo(u[j].y); a3 += bfhi(u[j].y);
                ae += te[j];
            }
        }
        for (; i < m; ++i) {   // tail singles: half-wave 0 only
            const int si = __builtin_amdgcn_readlane(s, i);
            const int ei = __builtin_amdgcn_readlane(e, i);
            if (g == 0) {
                const uint2 uu = *(const uint2*)(hbase + (size_t)si * D_NEIGH);
                a0 += bflo(uu.x); a1 += bfhi(uu.x);
                a2 += bflo(uu.y); a3 += bfhi(uu.y);
                ae += __builtin_nontemporal_load(ebase + (size_t)ei * D_EDGE);
            }
        }
    }

    a0 += __shfl_xor(a0, 32); a1 += __shfl_xor(a1, 32);
    a2 += __shfl_xor(a2, 32); a3 += __shfl_xor(a3, 32);
    ae += __shfl_xor(ae, 32);

    if (lane < 32) {
        const float inv = 1.0f / (float)(deg > 0 ? deg : 1);
        ushort* o = hnb + (size_t)d * D_HN;
        *(ushort4*)(o + 4 * ll) = make_ushort4(f2bf(a0 * inv), f2bf(a1 * inv),
                                               f2bf(a2 * inv), f2bf(a3 * inv));
        o[128 + ll] = f2bf(ae * inv);
    }
}

// ---------------- Fused bf16-MFMA GEMM + ReLU + row-L2-norm ----------------
// 128 rows x 256 cols, 512 threads (8 waves 4x2). X: LDS double-buffered
// (one barrier per K-step). W: B-fragments from L2-resident Wb, no LDS.

#define GBM 128

__global__ __launch_bounds__(512) void k_gemm_norm(const float* __restrict__ h_self,
                                                   const ushort* __restrict__ hnb,
                                                   const ushort* __restrict__ Wb,
                                                   float* __restrict__ out) {
    __shared__ __align__(16) ushort Xs[2][GBM * 40];
    __shared__ float rsum[2][GBM];
    __shared__ float invn[GBM];

    const int tid = threadIdx.x;
    const int lane = tid & 63;
    const int wid = tid >> 6;
    const int wm = wid >> 1;          // 0..3: row-group of 32
    const int wn = wid & 1;           // 0..1: col-group of 128
    const int brow = blockIdx.x * GBM;
    const int xrow = tid >> 2, xpart = tid & 3;   // stage: 8 bf16 per thread
    const int koff8 = lane >> 4, rsel = lane & 15;

    f32x4 acc[2][8] = {};

    auto stageX = [&](int t, int bufi) {
        const int k0 = t * 32;
        const int gr = brow + xrow;
        ushort4 v0 = make_ushort4(0, 0, 0, 0), v1 = v0;
        if (gr < N_DST) {
            if (k0 < 128) {
                const float* sp = h_self + (size_t)gr * D_SELF + k0 + xpart * 8;
                float4 f0 = *(const float4*)(sp);
                float4 f1 = *(const float4*)(sp + 4);
                v0 = make_ushort4(f2bf(f0.x), f2bf(f0.y), f2bf(f0.z), f2bf(f0.w));
                v1 = make_ushort4(f2bf(f1.x), f2bf(f1.y), f2bf(f1.z), f2bf(f1.w));
            } else {
                const ushort* sp = hnb + (size_t)gr * D_HN + (k0 - 128) + xpart * 8;
                v0 = *(const ushort4*)(sp);
                v1 = *(const ushort4*)(sp + 4);
            }
        }
        *(ushort4*)&Xs[bufi][xrow * 40 + xpart * 8] = v0;
        *(ushort4*)&Xs[bufi][xrow * 40 + xpart * 8 + 4] = v1;
    };

    stageX(0, 0);
    __syncthreads();

    for (int t = 0; t < 9; t++) {
        if (t < 8) stageX(t + 1, (t + 1) & 1);
        s16x8 af[2], bf[8];
#pragma unroll
        for (int fi = 0; fi < 2; fi++)
            af[fi] = *(const s16x8*)&Xs[t & 1][(wm * 32 + fi * 16 + rsel) * 40 + koff8 * 8];
#pragma unroll
        for (int fj = 0; fj < 8; fj++)
            bf[fj] = *(const s16x8*)&Wb[((size_t)(t * 4 + koff8) * 256 +
                                         (wn * 128 + fj * 16 + rsel)) * 8];
#pragma unroll
        for (int fi = 0; fi < 2; fi++)
#pragma unroll
            for (int fj = 0; fj < 8; fj++)
                acc[fi][fj] = __builtin_amdgcn_mfma_f32_16x16x32_bf16(af[fi], bf[fj], acc[fi][fj], 0, 0, 0);
        __syncthreads();
    }

    // relu + row sum-of-squares (C/D: col=lane&15, row=(lane>>4)*4+reg)
    float ss[2][4];
#pragma unroll
    for (int fi = 0; fi < 2; fi++)
#pragma unroll
        for (int j = 0; j < 4; j++) {
            float s = 0.f;
#pragma unroll
            for (int fj = 0; fj < 8; fj++) {
                float z = fmaxf(acc[fi][fj][j], 0.f);
                acc[fi][fj][j] = z;
                s += z * z;
            }
            ss[fi][j] = s;
        }
#pragma unroll
    for (int m = 1; m < 16; m <<= 1)
#pragma unroll
        for (int fi = 0; fi < 2; fi++)
#pragma unroll
            for (int j = 0; j < 4; j++) ss[fi][j] += __shfl_xor(ss[fi][j], m);
    if ((lane & 15) == 0) {
        const int gg = lane >> 4;
#pragma unroll
        for (int fi = 0; fi < 2; fi++)
#pragma unroll
            for (int j = 0; j < 4; j++)
                rsum[wn][wm * 32 + fi * 16 + gg * 4 + j] = ss[fi][j];
    }
    __syncthreads();
    if (tid < GBM) {
        float t = rsum[0][tid] + rsum[1][tid];
        invn[tid] = (t > 0.f) ? 1.f / sqrtf(t) : 1.f;
    }
    __syncthreads();

#pragma unroll
    for (int fi = 0; fi < 2; fi++)
#pragma unroll
        for (int j = 0; j < 4; j++) {
            const int rl = wm * 32 + fi * 16 + (lane >> 4) * 4 + j;
            const int row = brow + rl;
            if (row < N_DST) {
                const float iv = invn[rl];
#pragma unroll
                for (int fj = 0; fj < 8; fj++)
                    out[(size_t)row * D_OUT + wn * 128 + fj * 16 + (lane & 15)] = acc[fi][fj][j] * iv;
            }
        }
}

// ---------------- launch ----------------

extern "C" void kernel_launch(void* const* d_in, const int* in_sizes, int n_in,
                              void* d_out, int out_size, void* d_ws, size_t ws_size,
                              hipStream_t stream) {
    const float* h_neigh = (const float*)d_in[0];
    const float* h_self  = (const float*)d_in[1];
    const float* ef      = (const float*)d_in[2];
    const int*   src     = (const int*)d_in[3];
    const int*   dst     = (const int*)d_in[4];
    const float* Wself   = (const float*)d_in[5];
    const float* Wneigh  = (const float*)d_in[6];
    float* out = (float*)d_out;

    char* ws = (char*)d_ws;
    const size_t PKB = (size_t)NB << CAPSH;           // 3,211,264 entries
    const size_t need_new = 524288ull + 2 * PKB * 8 + 12800000ull + 16000000ull + 147456ull; // ~81MB

    if (ws_size >= need_new) {
        int*   gcur0 = (int*)(ws + 0);                 // 196*16 ints (zeroed)
        int2*  rs2   = (int2*)(ws + 16384);            // 50000 int2, ends 416384
        int2*  pk1   = (int2*)(ws + 524288);           // 25.7MB
        int2*  pk2   = (int2*)(ws + 524288 + PKB * 8); // 25.7MB
        ushort* hb   = (ushort*)(ws + 524288 + 2 * PKB * 8);           // 12.8MB
        ushort* hnb  = (ushort*)((char*)hb + 12800000);                // 16MB
        ushort* Wb   = (ushort*)((char*)hnb + 16000000);               // 147KB

        hipMemsetAsync(gcur0, 0, NB * CPAD * sizeof(int), stream);
        k_cvtall<<<6286, 256, 0, stream>>>(h_neigh, hb, Wself, Wneigh, Wb);
        k_scat1<<<256, 256, 0, stream>>>(dst, src, gcur0, pk1, N_EDGES);
        k_scat2<<<NB, 1024, 0, stream>>>(gcur0, pk1, pk2, rs2);
        k_agg<<<N_DST, 64, 0, stream>>>(rs2, pk2, hb, ef, hnb);
        k_gemm_norm<<<(N_DST + GBM - 1) / GBM, 512, 0, stream>>>(h_self, hnb, Wb, out);
    } else {
        // fallback: simple CSR (needs ~43.4MB)
        int* deg       = (int*)(ws + 0);
        int* row_start = (int*)(ws + 262144);
        int* cursor    = (int*)(ws + 524288);
        int2* pk       = (int2*)(ws + 786432);            // ->13586432
        ushort* hb     = (ushort*)(ws + 13586432);        // ->26386432
        ushort* hnb    = (ushort*)(ws + 26386432);        // ->42386432
        ushort* Wb     = (ushort*)(ws + 42386432);        // ->42533888
        int2* rs2      = (int2*)(ws + 42533888);          // ->42933888

        hipMemsetAsync(deg, 0, N_DST * sizeof(int), stream);
        k_cvtall<<<6286, 256, 0, stream>>>(h_neigh, hb, Wself, Wneigh, Wb);
        k_deg<<<(N_EDGES + 255) / 256, 256, 0, stream>>>(dst, deg, N_EDGES);
        k_scan<<<1, 1024, 0, stream>>>(deg, row_start, cursor);
        k_fill<<<(N_EDGES + 255) / 256, 256, 0, stream>>>(dst, src, cursor, pk, N_EDGES);
        k_mkrs2<<<(N_DST + 255) / 256, 256, 0, stream>>>(row_start, rs2);
        k_agg<<<N_DST, 64, 0, stream>>>(rs2, pk, hb, ef, hnb);
        k_gemm_norm<<<(N_DST + GBM - 1) / GBM, 512, 0, stream>>>(h_self, hnb, Wb, out);
    }
}

// Round 12
// 171.388 us; speedup vs baseline: 10.8889x; 1.0045x over previous
//
#include <hip/hip_runtime.h>

#define N_SRC 50000
#define N_DST 50000
#define N_EDGES 1600000
#define D_NEIGH 128
#define D_SELF 128
#define D_EDGE 32
#define D_OUT 256
#define K_TOT 288   // [0,128)=self(f32), [128,288)=hn(bf16)
#define D_HN 160

#define NB 196      // coarse buckets of 256 dst nodes
#define CPAD 16     // one counter per 64B line
#define CHUNK 2048
#define CAPSH 14    // 16384-entry padded window per bucket
#define NSCAT1 256  // scatter blocks inside k_pre

typedef float f32x4 __attribute__((ext_vector_type(4)));
typedef short s16x8 __attribute__((ext_vector_type(8)));
typedef float fv4 __attribute__((ext_vector_type(4)));         // nontemporal-compatible
typedef unsigned short uv4 __attribute__((ext_vector_type(4)));

__device__ __forceinline__ ushort f2bf(float x) {
    unsigned b = __float_as_uint(x);
    return (ushort)((b + 0x7fffu + ((b >> 16) & 1u)) >> 16);  // RNE
}
__device__ __forceinline__ float bflo(unsigned u) { return __uint_as_float(u << 16); }
__device__ __forceinline__ float bfhi(unsigned u) { return __uint_as_float(u & 0xffff0000u); }

// ---------------- fused pre-pass: radix scatter ∥ hb cvt ∥ Wb cvt ----------
// blocks [0,NSCAT1): LDS-staged scatter into padded bucket windows.
// blocks [NSCAT1, NSCAT1+6250): h_neigh f32->bf16.
// blocks [NSCAT1+6250, +36): W -> bf16 fragment layout Wb[t][koff8][c][8].

__global__ __launch_bounds__(256) void k_pre(const int* __restrict__ dst,
                                             const int* __restrict__ src,
                                             int* __restrict__ gcur0,
                                             int2* __restrict__ pk1,
                                             const float* __restrict__ h_neigh,
                                             ushort* __restrict__ hb,
                                             const float* __restrict__ Wself,
                                             const float* __restrict__ Wneigh,
                                             ushort* __restrict__ Wb) {
    __shared__ int hist[NB];
    __shared__ int lbase[NB];
    __shared__ int gbase[NB];
    __shared__ int2 stage[CHUNK];
    const int blk = blockIdx.x;
    const int tid = threadIdx.x;

    if (blk >= NSCAT1) {
        const int bb = blk - NSCAT1;
        if (bb < 6250) {                       // hb convert (6.4M elems / 4)
            const int i = bb * 256 + tid;
            float4 f = ((const float4*)h_neigh)[i];
            ((ushort4*)hb)[i] = make_ushort4(f2bf(f.x), f2bf(f.y), f2bf(f.z), f2bf(f.w));
        } else {                               // Wb convert
            const int q = (bb - 6250) * 256 + tid;
            if (q >= 9 * 4 * 256) return;
            const int t = q >> 10;
            const int r = q & 1023;
            const int k8 = r >> 8;
            const int c = r & 255;
            const int kb = t * 32 + k8 * 8;
            const float* p = (kb < 128) ? (Wself + (size_t)c * D_SELF + kb)
                                        : (Wneigh + (size_t)c * D_HN + (kb - 128));
            float4 f0 = *(const float4*)(p);
            float4 f1 = *(const float4*)(p + 4);
            ushort* o = Wb + (size_t)q * 8;
            *(ushort4*)(o)     = make_ushort4(f2bf(f0.x), f2bf(f0.y), f2bf(f0.z), f2bf(f0.w));
            *(ushort4*)(o + 4) = make_ushort4(f2bf(f1.x), f2bf(f1.y), f2bf(f1.z), f2bf(f1.w));
        }
        return;
    }

    // ---- scatter part (blocks 0..NSCAT1-1), fixed stride NSCAT1*CHUNK ----
    const int n = N_EDGES;
    for (int c0 = blk * CHUNK; c0 < n; c0 += NSCAT1 * CHUNK) {
        const int m = min(CHUNK, n - c0);
        for (int t = tid; t < NB; t += 256) hist[t] = 0;
        __syncthreads();
        int d8[8], s8[8];
#pragma unroll
        for (int j = 0; j < 8; j++) {
            const int i = c0 + j * 256 + tid;
            if (i < n) { d8[j] = dst[i]; s8[j] = src[i]; atomicAdd(&hist[d8[j] >> 8], 1); }
        }
        __syncthreads();
        if (tid == 0) {
            int ex = 0;
            for (int b = 0; b < NB; b++) { lbase[b] = ex; ex += hist[b]; }
        }
        __syncthreads();
        for (int t = tid; t < NB; t += 256)
            gbase[t] = hist[t] ? atomicAdd(&gcur0[t * CPAD], hist[t]) : 0;
        __syncthreads();
        for (int t = tid; t < NB; t += 256) hist[t] = lbase[t];
        __syncthreads();
#pragma unroll
        for (int j = 0; j < 8; j++) {
            const int i = c0 + j * 256 + tid;
            if (i < n) {
                const unsigned cb = (unsigned)d8[j] >> 8;
                const int p = atomicAdd(&hist[cb], 1);
                stage[p] = make_int2(i, (int)((unsigned)s8[j] |
                                              (((unsigned)d8[j] & 255u) << 16) | (cb << 24)));
            }
        }
        __syncthreads();
        for (int t = tid; t < m; t += 256) {
            int2 v = stage[t];
            const int cb = (v.y >> 24) & 255;
            v.y &= 0x00FFFFFF;
            pk1[((size_t)cb << CAPSH) + gbase[cb] + (t - lbase[cb])] = v;
        }
        __syncthreads();
    }
}

// ---------------- pass B: per-bucket sort -> per-dst runs + rs2(start,end) ---

__global__ __launch_bounds__(1024) void k_scat2(const int* __restrict__ gcur0,
                                                const int2* __restrict__ pk1,
                                                int2* __restrict__ pk2,
                                                int2* __restrict__ rs2) {
    __shared__ int part[256];
    __shared__ int cur[256];
    const int b = blockIdx.x;
    const int n = gcur0[b * CPAD];
    const int base = b << CAPSH;
    const int tid = threadIdx.x;
    if (tid < 256) part[tid] = 0;
    __syncthreads();
    for (int i = tid; i < n; i += 1024)
        atomicAdd(&part[(pk1[base + i].y >> 16) & 255], 1);
    __syncthreads();
    const int c0 = (tid < 256) ? part[tid] : 0;
    __syncthreads();
    for (int off = 1; off < 256; off <<= 1) {
        int v = 0;
        if (tid < 256 && tid >= off) v = part[tid - off];
        __syncthreads();
        if (tid < 256) part[tid] += v;
        __syncthreads();
    }
    if (tid < 256) {
        const int pfx = part[tid] - c0;   // exclusive
        cur[tid] = pfx;
        const int gn = b * 256 + tid;
        if (gn < N_DST) rs2[gn] = make_int2(base + pfx, base + pfx + c0);
    }
    __syncthreads();
    for (int i = tid; i < n; i += 1024) {
        int2 v = pk1[base + i];
        const int dl = (v.y >> 16) & 255;
        const int p = atomicAdd(&cur[dl], 1);
        pk2[base + p] = make_int2(v.x, v.y & 0xFFFF);
    }
}

// ---------------- fallback CSR path (small ws) ----------------

__global__ void k_cvtall(const float* __restrict__ in, ushort* __restrict__ hb,
                         const float* __restrict__ Wself, const float* __restrict__ Wneigh,
                         ushort* __restrict__ Wb) {
    const int b = blockIdx.x;
    if (b < 6250) {
        const int i = b * 256 + threadIdx.x;
        float4 f = ((const float4*)in)[i];
        ((ushort4*)hb)[i] = make_ushort4(f2bf(f.x), f2bf(f.y), f2bf(f.z), f2bf(f.w));
    } else {
        const int q = (b - 6250) * 256 + threadIdx.x;
        if (q >= 9 * 4 * 256) return;
        const int t = q >> 10;
        const int r = q & 1023;
        const int k8 = r >> 8;
        const int c = r & 255;
        const int kb = t * 32 + k8 * 8;
        const float* p = (kb < 128) ? (Wself + (size_t)c * D_SELF + kb)
                                    : (Wneigh + (size_t)c * D_HN + (kb - 128));
        float4 f0 = *(const float4*)(p);
        float4 f1 = *(const float4*)(p + 4);
        ushort* o = Wb + (size_t)q * 8;
        *(ushort4*)(o)     = make_ushort4(f2bf(f0.x), f2bf(f0.y), f2bf(f0.z), f2bf(f0.w));
        *(ushort4*)(o + 4) = make_ushort4(f2bf(f1.x), f2bf(f1.y), f2bf(f1.z), f2bf(f1.w));
    }
}

__global__ void k_deg(const int* __restrict__ dst, int* __restrict__ deg, int n) {
    int i = blockIdx.x * blockDim.x + threadIdx.x;
    if (i < n) atomicAdd(&deg[dst[i]], 1);
}

__global__ __launch_bounds__(1024) void k_scan(const int* __restrict__ deg,
                                               int* __restrict__ row_start,
                                               int* __restrict__ cursor) {
    __shared__ int part[1024];
    const int t = threadIdx.x;
    const int CH = (N_DST + 1023) / 1024;
    const int b = t * CH;
    int s = 0;
    for (int i = 0; i < CH; i++) { int idx = b + i; if (idx < N_DST) s += deg[idx]; }
    part[t] = s;
    __syncthreads();
    for (int off = 1; off < 1024; off <<= 1) {
        int v = (t >= off) ? part[t - off] : 0;
        __syncthreads();
        part[t] += v;
        __syncthreads();
    }
    int ex = (t == 0) ? 0 : part[t - 1];
    for (int i = 0; i < CH; i++) {
        int idx = b + i;
        if (idx < N_DST) { row_start[idx] = ex; cursor[idx] = ex; ex += deg[idx]; }
    }
    if (t == 1023) row_start[N_DST] = part[1023];
}

__global__ void k_fill(const int* __restrict__ dst, const int* __restrict__ src,
                       int* __restrict__ cursor, int2* __restrict__ pk, int n) {
    int i = blockIdx.x * blockDim.x + threadIdx.x;
    if (i < n) {
        int p = atomicAdd(&cursor[dst[i]], 1);
        pk[p] = make_int2(i, src[i]);
    }
}

__global__ void k_mkrs2(const int* __restrict__ row_start, int2* __restrict__ rs2) {
    int i = blockIdx.x * blockDim.x + threadIdx.x;
    if (i < N_DST) rs2[i] = make_int2(row_start[i], row_start[i + 1]);
}

// ---------------- Aggregation: one wave per dst node ----------------
// Half-wave split gathers. Zero-reuse streams (pk, ef) are NON-TEMPORAL so
// the 12.8MB hb working set stays cache-resident (410MB of re-reads).

__global__ __launch_bounds__(64) void k_agg(const int2* __restrict__ rs2,
                                            const int2* __restrict__ pk,
                                            const ushort* __restrict__ hb,
                                            const float* __restrict__ ef,
                                            ushort* __restrict__ hnb) {
    const int d = blockIdx.x;
    const int lane = threadIdx.x;
    const int ll = lane & 31;
    const int g = lane >> 5;
    const int2 se = rs2[d];
    const int start = se.x, end = se.y;
    const int deg = end - start;
    float a0 = 0.f, a1 = 0.f, a2 = 0.f, a3 = 0.f, ae = 0.f;
    const ushort* hbase = hb + 4 * ll;
    const float* ebase = ef + ll;

    for (int c = start; c < end; c += 64) {
        const int rem = end - c;
        const int m = rem < 64 ? rem : 64;
        int e = 0, s = 0;
        if (lane < m) {
            unsigned long long pv =
                __builtin_nontemporal_load((const unsigned long long*)&pk[c + lane]);
            e = (int)(unsigned)pv;
            s = (int)(unsigned)(pv >> 32);
        }
        int i = 0;
        for (; i + 16 <= m; i += 16) {
            uint2 u[8];
            float te[8];
#pragma unroll
            for (int j = 0; j < 8; j++) {
                const int sj = __shfl(s, i + 2 * j + g);
                u[j] = *(const uint2*)(hbase + (size_t)sj * D_NEIGH);
            }
#pragma unroll
            for (int j = 0; j < 8; j++) {
                const int ee = __shfl(e, i + 2 * j + g);
                te[j] = __builtin_nontemporal_load(ebase + (size_t)ee * D_EDGE);
            }
#pragma unroll
            for (int j = 0; j < 8; j++) {
                a0 += bflo(u[j].x); a1 += bfhi(u[j].x);
                a2 += bflo(u[j].y); a3 += bfhi(u[j].y);
                ae += te[j];
            }
        }
        for (; i + 8 <= m; i += 8) {
            uint2 u[4];
            float te[4];
#pragma unroll
            for (int j = 0; j < 4; j++) {
                const int sj = __shfl(s, i + 2 * j + g);
                u[j] = *(const uint2*)(hbase + (size_t)sj * D_NEIGH);
            }
#pragma unroll
            for (int j = 0; j < 4; j++) {
                const int ee = __shfl(e, i + 2 * j + g);
                te[j] = __builtin_nontemporal_load(ebase + (size_t)ee * D_EDGE);
            }
#pragma unroll
            for (int j = 0; j < 4; j++) {
                a0 += bflo(u[j].x); a1 += bfhi(u[j].x);
                a2 += bflo(u[j].y); a3 += bfhi(u[j].y);
                ae += te[j];
            }
        }
        for (; i < m; ++i) {   // tail singles: half-wave 0 only
            const int si = __builtin_amdgcn_readlane(s, i);
            const int ei = __builtin_amdgcn_readlane(e, i);
            if (g == 0) {
                const uint2 uu = *(const uint2*)(hbase + (size_t)si * D_NEIGH);
                a0 += bflo(uu.x); a1 += bfhi(uu.x);
                a2 += bflo(uu.y); a3 += bfhi(uu.y);
                ae += __builtin_nontemporal_load(ebase + (size_t)ei * D_EDGE);
            }
        }
    }

    a0 += __shfl_xor(a0, 32); a1 += __shfl_xor(a1, 32);
    a2 += __shfl_xor(a2, 32); a3 += __shfl_xor(a3, 32);
    ae += __shfl_xor(ae, 32);

    if (lane < 32) {
        const float inv = 1.0f / (float)(deg > 0 ? deg : 1);
        ushort* o = hnb + (size_t)d * D_HN;
        *(ushort4*)(o + 4 * ll) = make_ushort4(f2bf(a0 * inv), f2bf(a1 * inv),
                                               f2bf(a2 * inv), f2bf(a3 * inv));
        o[128 + ll] = f2bf(ae * inv);
    }
}

// ---------------- Fused bf16-MFMA GEMM + ReLU + row-L2-norm ----------------
// 128 rows x 256 cols, 512 threads (8 waves 4x2). X: LDS double-buffered,
// one barrier per K-step; staging loads non-temporal via ext_vector types.
// W: B-fragments from L2-resident Wb. Output stores non-temporal.

#define GBM 128

__global__ __launch_bounds__(512) void k_gemm_norm(const float* __restrict__ h_self,
                                                   const ushort* __restrict__ hnb,
                                                   const ushort* __restrict__ Wb,
                                                   float* __restrict__ out) {
    __shared__ __align__(16) ushort Xs[2][GBM * 40];
    __shared__ float rsum[2][GBM];
    __shared__ float invn[GBM];

    const int tid = threadIdx.x;
    const int lane = tid & 63;
    const int wid = tid >> 6;
    const int wm = wid >> 1;          // 0..3: row-group of 32
    const int wn = wid & 1;           // 0..1: col-group of 128
    const int brow = blockIdx.x * GBM;
    const int xrow = tid >> 2, xpart = tid & 3;   // stage: 8 bf16 per thread
    const int koff8 = lane >> 4, rsel = lane & 15;

    f32x4 acc[2][8] = {};

    auto stageX = [&](int t, int bufi) {
        const int k0 = t * 32;
        const int gr = brow + xrow;
        uv4 v0 = (uv4)0, v1 = (uv4)0;
        if (gr < N_DST) {
            if (k0 < 128) {
                const float* sp = h_self + (size_t)gr * D_SELF + k0 + xpart * 8;
                fv4 f0 = __builtin_nontemporal_load((const fv4*)(sp));
                fv4 f1 = __builtin_nontemporal_load((const fv4*)(sp + 4));
                v0 = (uv4){f2bf(f0.x), f2bf(f0.y), f2bf(f0.z), f2bf(f0.w)};
                v1 = (uv4){f2bf(f1.x), f2bf(f1.y), f2bf(f1.z), f2bf(f1.w)};
            } else {
                const ushort* sp = hnb + (size_t)gr * D_HN + (k0 - 128) + xpart * 8;
                v0 = __builtin_nontemporal_load((const uv4*)(sp));
                v1 = __builtin_nontemporal_load((const uv4*)(sp + 4));
            }
        }
        *(uv4*)&Xs[bufi][xrow * 40 + xpart * 8] = v0;
        *(uv4*)&Xs[bufi][xrow * 40 + xpart * 8 + 4] = v1;
    };

    stageX(0, 0);
    __syncthreads();

    for (int t = 0; t < 9; t++) {
        if (t < 8) stageX(t + 1, (t + 1) & 1);
        s16x8 af[2], bf[8];
#pragma unroll
        for (int fi = 0; fi < 2; fi++)
            af[fi] = *(const s16x8*)&Xs[t & 1][(wm * 32 + fi * 16 + rsel) * 40 + koff8 * 8];
#pragma unroll
        for (int fj = 0; fj < 8; fj++)
            bf[fj] = *(const s16x8*)&Wb[((size_t)(t * 4 + koff8) * 256 +
                                         (wn * 128 + fj * 16 + rsel)) * 8];
#pragma unroll
        for (int fi = 0; fi < 2; fi++)
#pragma unroll
            for (int fj = 0; fj < 8; fj++)
                acc[fi][fj] = __builtin_amdgcn_mfma_f32_16x16x32_bf16(af[fi], bf[fj], acc[fi][fj], 0, 0, 0);
        __syncthreads();
    }

    // relu + row sum-of-squares (C/D: col=lane&15, row=(lane>>4)*4+reg)
    float ss[2][4];
#pragma unroll
    for (int fi = 0; fi < 2; fi++)
#pragma unroll
        for (int j = 0; j < 4; j++) {
            float s = 0.f;
#pragma unroll
            for (int fj = 0; fj < 8; fj++) {
                float z = fmaxf(acc[fi][fj][j], 0.f);
                acc[fi][fj][j] = z;
                s += z * z;
            }
            ss[fi][j] = s;
        }
#pragma unroll
    for (int m = 1; m < 16; m <<= 1)
#pragma unroll
        for (int fi = 0; fi < 2; fi++)
#pragma unroll
            for (int j = 0; j < 4; j++) ss[fi][j] += __shfl_xor(ss[fi][j], m);
    if ((lane & 15) == 0) {
        const int gg = lane >> 4;
#pragma unroll
        for (int fi = 0; fi < 2; fi++)
#pragma unroll
            for (int j = 0; j < 4; j++)
                rsum[wn][wm * 32 + fi * 16 + gg * 4 + j] = ss[fi][j];
    }
    __syncthreads();
    if (tid < GBM) {
        float t = rsum[0][tid] + rsum[1][tid];
        invn[tid] = (t > 0.f) ? 1.f / sqrtf(t) : 1.f;
    }
    __syncthreads();

#pragma unroll
    for (int fi = 0; fi < 2; fi++)
#pragma unroll
        for (int j = 0; j < 4; j++) {
            const int rl = wm * 32 + fi * 16 + (lane >> 4) * 4 + j;
            const int row = brow + rl;
            if (row < N_DST) {
                const float iv = invn[rl];
#pragma unroll
                for (int fj = 0; fj < 8; fj++)
                    __builtin_nontemporal_store(acc[fi][fj][j] * iv,
                        &out[(size_t)row * D_OUT + wn * 128 + fj * 16 + (lane & 15)]);
            }
        }
}

// ---------------- launch ----------------

extern "C" void kernel_launch(void* const* d_in, const int* in_sizes, int n_in,
                              void* d_out, int out_size, void* d_ws, size_t ws_size,
                              hipStream_t stream) {
    const float* h_neigh = (const float*)d_in[0];
    const float* h_self  = (const float*)d_in[1];
    const float* ef      = (const float*)d_in[2];
    const int*   src     = (const int*)d_in[3];
    const int*   dst     = (const int*)d_in[4];
    const float* Wself   = (const float*)d_in[5];
    const float* Wneigh  = (const float*)d_in[6];
    float* out = (float*)d_out;

    char* ws = (char*)d_ws;
    const size_t PKB = (size_t)NB << CAPSH;           // 3,211,264 entries
    const size_t need_new = 524288ull + 2 * PKB * 8 + 12800000ull + 16000000ull + 147456ull; // ~81MB

    if (ws_size >= need_new) {
        int*   gcur0 = (int*)(ws + 0);                 // 196*16 ints (zeroed)
        int2*  rs2   = (int2*)(ws + 16384);            // 50000 int2
        int2*  pk1   = (int2*)(ws + 524288);           // 25.7MB
        int2*  pk2   = (int2*)(ws + 524288 + PKB * 8); // 25.7MB
        ushort* hb   = (ushort*)(ws + 524288 + 2 * PKB * 8);   // 12.8MB
        ushort* hnb  = (ushort*)((char*)hb + 12800000);        // 16MB
        ushort* Wb   = (ushort*)((char*)hnb + 16000000);       // 147KB

        hipMemsetAsync(gcur0, 0, NB * CPAD * sizeof(int), stream);
        k_pre<<<NSCAT1 + 6250 + 36, 256, 0, stream>>>(dst, src, gcur0, pk1,
                                                      h_neigh, hb, Wself, Wneigh, Wb);
        k_scat2<<<NB, 1024, 0, stream>>>(gcur0, pk1, pk2, rs2);
        k_agg<<<N_DST, 64, 0, stream>>>(rs2, pk2, hb, ef, hnb);
        k_gemm_norm<<<(N_DST + GBM - 1) / GBM, 512, 0, stream>>>(h_self, hnb, Wb, out);
    } else {
        // fallback: simple CSR (needs ~43.4MB)
        int* deg       = (int*)(ws + 0);
        int* row_start = (int*)(ws + 262144);
        int* cursor    = (int*)(ws + 524288);
        int2* pk       = (int2*)(ws + 786432);            // ->13586432
        ushort* hb     = (ushort*)(ws + 13586432);        // ->26386432
        ushort* hnb    = (ushort*)(ws + 26386432);        // ->42386432
        ushort* Wb     = (ushort*)(ws + 42386432);        // ->42533888
        int2* rs2      = (int2*)(ws + 42533888);          // ->42933888

        hipMemsetAsync(deg, 0, N_DST * sizeof(int), stream);
        k_cvtall<<<6286, 256, 0, stream>>>(h_neigh, hb, Wself, Wneigh, Wb);
        k_deg<<<(N_EDGES + 255) / 256, 256, 0, stream>>>(dst, deg, N_EDGES);
        k_scan<<<1, 1024, 0, stream>>>(deg, row_start, cursor);
        k_fill<<<(N_EDGES + 255) / 256, 256, 0, stream>>>(dst, src, cursor, pk, N_EDGES);
        k_mkrs2<<<(N_DST + 255) / 256, 256, 0, stream>>>(row_start, rs2);
        k_agg<<<N_DST, 64, 0, stream>>>(rs2, pk, hb, ef, hnb);
        k_gemm_norm<<<(N_DST + GBM - 1) / GBM, 512, 0, stream>>>(h_self, hnb, Wb, out);
    }
}

// Round 13
// 151.050 us; speedup vs baseline: 12.3550x; 1.1346x over previous
//
#include <hip/hip_runtime.h>

#define N_SRC 50000
#define N_DST 50000
#define N_EDGES 1600000
#define D_NEIGH 128
#define D_SELF 128
#define D_EDGE 32
#define D_OUT 256
#define K_TOT 288   // [0,128)=self(f32), [128,288)=hn(bf16)
#define D_HN 160

#define NB 196      // coarse buckets of 256 dst nodes
#define CPAD 16     // one counter per 64B line
#define CHUNK 2048
#define CAPSH 14    // 16384-entry padded window per bucket
#define NSCAT1 256  // scatter blocks inside k_pre

typedef float f32x4 __attribute__((ext_vector_type(4)));
typedef short s16x8 __attribute__((ext_vector_type(8)));
typedef float fv4 __attribute__((ext_vector_type(4)));
typedef float fv2 __attribute__((ext_vector_type(2)));
typedef unsigned short uv4 __attribute__((ext_vector_type(4)));

__device__ __forceinline__ ushort f2bf(float x) {
    unsigned b = __float_as_uint(x);
    return (ushort)((b + 0x7fffu + ((b >> 16) & 1u)) >> 16);  // RNE
}
__device__ __forceinline__ float bflo(unsigned u) { return __uint_as_float(u << 16); }
__device__ __forceinline__ float bfhi(unsigned u) { return __uint_as_float(u & 0xffff0000u); }

// ---------------- OCP e4m3 encode/decode (HW cvt if available) --------------

#if defined(__has_builtin)
#if __has_builtin(__builtin_amdgcn_cvt_pk_fp8_f32) && __has_builtin(__builtin_amdgcn_cvt_pk_f32_fp8)
#define FP8_HW 1
#endif
#endif

__device__ __forceinline__ unsigned enc_fp8_scalar(float x) {  // manual OCP e4m3fn, FTZ
    unsigned b = __float_as_uint(x);
    const unsigned s = b >> 31;
    float ax = fabsf(x);
    ax = fminf(ax, 448.f);
    if (ax < 0.015625f) return s << 7;            // FTZ below 2^-6
    unsigned ab = __float_as_uint(ax);
    unsigned lsb = (ab >> 20) & 1u;
    unsigned b2 = ab + 0x7FFFFu + lsb;            // RNE into 3-bit mantissa
    unsigned e = ((b2 >> 23) & 0xFFu) - 120u;     // rebias 127->7
    unsigned m = (b2 >> 20) & 7u;
    if (e > 15u) { e = 15u; m = 6u; }             // clamp to 448
    return (s << 7) | (e << 3) | m;
}

__device__ __forceinline__ unsigned enc_fp8x4(float4 f) {
#ifdef FP8_HW
    int r = 0;
    r = __builtin_amdgcn_cvt_pk_fp8_f32(f.x, f.y, r, false);
    r = __builtin_amdgcn_cvt_pk_fp8_f32(f.z, f.w, r, true);
    return (unsigned)r;
#else
    return enc_fp8_scalar(f.x) | (enc_fp8_scalar(f.y) << 8) |
           (enc_fp8_scalar(f.z) << 16) | (enc_fp8_scalar(f.w) << 24);
#endif
}

__device__ __forceinline__ float dec_fp8_scalar(unsigned u) {  // u: low 8 bits, FTZ
    unsigned e = (u >> 3) & 15u;
    unsigned bits = ((u & 0x80u) << 24) | (((u & 0x7Fu) << 20) + (120u << 23));
    return (e == 0) ? 0.f : __uint_as_float(bits);
}

// decode 4 fp8 from one u32 into f[0..3]
__device__ __forceinline__ void dec_fp8x4(unsigned u, float* f) {
#ifdef FP8_HW
    fv2 lo = __builtin_amdgcn_cvt_pk_f32_fp8(u, false);
    fv2 hi = __builtin_amdgcn_cvt_pk_f32_fp8(u, true);
    f[0] = lo.x; f[1] = lo.y; f[2] = hi.x; f[3] = hi.y;
#else
    f[0] = dec_fp8_scalar(u);
    f[1] = dec_fp8_scalar(u >> 8);
    f[2] = dec_fp8_scalar(u >> 16);
    f[3] = dec_fp8_scalar(u >> 24);
#endif
}

// ---------------- fused pre-pass: radix scatter ∥ hb cvt ∥ Wb cvt ----------
// blocks [0,NSCAT1): LDS-staged scatter into padded bucket windows.
// blocks [NSCAT1, NSCAT1+6250): h_neigh f32->fp8 e4m3 (hb, 6.4MB).
// blocks [NSCAT1+6250, +36): W -> bf16 fragment layout Wb[t][koff8][c][8].

__global__ __launch_bounds__(256) void k_pre(const int* __restrict__ dst,
                                             const int* __restrict__ src,
                                             int* __restrict__ gcur0,
                                             int2* __restrict__ pk1,
                                             const float* __restrict__ h_neigh,
                                             unsigned* __restrict__ hb,
                                             const float* __restrict__ Wself,
                                             const float* __restrict__ Wneigh,
                                             ushort* __restrict__ Wb) {
    __shared__ int hist[NB];
    __shared__ int lbase[NB];
    __shared__ int gbase[NB];
    __shared__ int2 stage[CHUNK];
    const int blk = blockIdx.x;
    const int tid = threadIdx.x;

    if (blk >= NSCAT1) {
        const int bb = blk - NSCAT1;
        if (bb < 6250) {                       // hb convert: 4 f32 -> 4 fp8 per thread
            const int i = bb * 256 + tid;
            float4 f = ((const float4*)h_neigh)[i];
            hb[i] = enc_fp8x4(f);
        } else {                               // Wb convert
            const int q = (bb - 6250) * 256 + tid;
            if (q >= 9 * 4 * 256) return;
            const int t = q >> 10;
            const int r = q & 1023;
            const int k8 = r >> 8;
            const int c = r & 255;
            const int kb = t * 32 + k8 * 8;
            const float* p = (kb < 128) ? (Wself + (size_t)c * D_SELF + kb)
                                        : (Wneigh + (size_t)c * D_HN + (kb - 128));
            float4 f0 = *(const float4*)(p);
            float4 f1 = *(const float4*)(p + 4);
            ushort* o = Wb + (size_t)q * 8;
            *(ushort4*)(o)     = make_ushort4(f2bf(f0.x), f2bf(f0.y), f2bf(f0.z), f2bf(f0.w));
            *(ushort4*)(o + 4) = make_ushort4(f2bf(f1.x), f2bf(f1.y), f2bf(f1.z), f2bf(f1.w));
        }
        return;
    }

    // ---- scatter part (blocks 0..NSCAT1-1), fixed stride NSCAT1*CHUNK ----
    const int n = N_EDGES;
    for (int c0 = blk * CHUNK; c0 < n; c0 += NSCAT1 * CHUNK) {
        const int m = min(CHUNK, n - c0);
        for (int t = tid; t < NB; t += 256) hist[t] = 0;
        __syncthreads();
        int d8[8], s8[8];
#pragma unroll
        for (int j = 0; j < 8; j++) {
            const int i = c0 + j * 256 + tid;
            if (i < n) { d8[j] = dst[i]; s8[j] = src[i]; atomicAdd(&hist[d8[j] >> 8], 1); }
        }
        __syncthreads();
        if (tid == 0) {
            int ex = 0;
            for (int b = 0; b < NB; b++) { lbase[b] = ex; ex += hist[b]; }
        }
        __syncthreads();
        for (int t = tid; t < NB; t += 256)
            gbase[t] = hist[t] ? atomicAdd(&gcur0[t * CPAD], hist[t]) : 0;
        __syncthreads();
        for (int t = tid; t < NB; t += 256) hist[t] = lbase[t];
        __syncthreads();
#pragma unroll
        for (int j = 0; j < 8; j++) {
            const int i = c0 + j * 256 + tid;
            if (i < n) {
                const unsigned cb = (unsigned)d8[j] >> 8;
                const int p = atomicAdd(&hist[cb], 1);
                stage[p] = make_int2(i, (int)((unsigned)s8[j] |
                                              (((unsigned)d8[j] & 255u) << 16) | (cb << 24)));
            }
        }
        __syncthreads();
        for (int t = tid; t < m; t += 256) {
            int2 v = stage[t];
            const int cb = (v.y >> 24) & 255;
            v.y &= 0x00FFFFFF;
            pk1[((size_t)cb << CAPSH) + gbase[cb] + (t - lbase[cb])] = v;
        }
        __syncthreads();
    }
}

// ---------------- pass B: per-bucket sort -> per-dst runs + rs2(start,end) ---

__global__ __launch_bounds__(1024) void k_scat2(const int* __restrict__ gcur0,
                                                const int2* __restrict__ pk1,
                                                int2* __restrict__ pk2,
                                                int2* __restrict__ rs2) {
    __shared__ int part[256];
    __shared__ int cur[256];
    const int b = blockIdx.x;
    const int n = gcur0[b * CPAD];
    const int base = b << CAPSH;
    const int tid = threadIdx.x;
    if (tid < 256) part[tid] = 0;
    __syncthreads();
    for (int i = tid; i < n; i += 1024)
        atomicAdd(&part[(pk1[base + i].y >> 16) & 255], 1);
    __syncthreads();
    const int c0 = (tid < 256) ? part[tid] : 0;
    __syncthreads();
    for (int off = 1; off < 256; off <<= 1) {
        int v = 0;
        if (tid < 256 && tid >= off) v = part[tid - off];
        __syncthreads();
        if (tid < 256) part[tid] += v;
        __syncthreads();
    }
    if (tid < 256) {
        const int pfx = part[tid] - c0;   // exclusive
        cur[tid] = pfx;
        const int gn = b * 256 + tid;
        if (gn < N_DST) rs2[gn] = make_int2(base + pfx, base + pfx + c0);
    }
    __syncthreads();
    for (int i = tid; i < n; i += 1024) {
        int2 v = pk1[base + i];
        const int dl = (v.y >> 16) & 255;
        const int p = atomicAdd(&cur[dl], 1);
        pk2[base + p] = make_int2(v.x, v.y & 0xFFFF);
    }
}

// ---------------- fallback CSR path (small ws) ----------------

__global__ void k_cvtall(const float* __restrict__ in, unsigned* __restrict__ hb,
                         const float* __restrict__ Wself, const float* __restrict__ Wneigh,
                         ushort* __restrict__ Wb) {
    const int b = blockIdx.x;
    if (b < 6250) {
        const int i = b * 256 + threadIdx.x;
        float4 f = ((const float4*)in)[i];
        hb[i] = enc_fp8x4(f);
    } else {
        const int q = (b - 6250) * 256 + threadIdx.x;
        if (q >= 9 * 4 * 256) return;
        const int t = q >> 10;
        const int r = q & 1023;
        const int k8 = r >> 8;
        const int c = r & 255;
        const int kb = t * 32 + k8 * 8;
        const float* p = (kb < 128) ? (Wself + (size_t)c * D_SELF + kb)
                                    : (Wneigh + (size_t)c * D_HN + (kb - 128));
        float4 f0 = *(const float4*)(p);
        float4 f1 = *(const float4*)(p + 4);
        ushort* o = Wb + (size_t)q * 8;
        *(ushort4*)(o)     = make_ushort4(f2bf(f0.x), f2bf(f0.y), f2bf(f0.z), f2bf(f0.w));
        *(ushort4*)(o + 4) = make_ushort4(f2bf(f1.x), f2bf(f1.y), f2bf(f1.z), f2bf(f1.w));
    }
}

__global__ void k_deg(const int* __restrict__ dst, int* __restrict__ deg, int n) {
    int i = blockIdx.x * blockDim.x + threadIdx.x;
    if (i < n) atomicAdd(&deg[dst[i]], 1);
}

__global__ __launch_bounds__(1024) void k_scan(const int* __restrict__ deg,
                                               int* __restrict__ row_start,
                                               int* __restrict__ cursor) {
    __shared__ int part[1024];
    const int t = threadIdx.x;
    const int CH = (N_DST + 1023) / 1024;
    const int b = t * CH;
    int s = 0;
    for (int i = 0; i < CH; i++) { int idx = b + i; if (idx < N_DST) s += deg[idx]; }
    part[t] = s;
    __syncthreads();
    for (int off = 1; off < 1024; off <<= 1) {
        int v = (t >= off) ? part[t - off] : 0;
        __syncthreads();
        part[t] += v;
        __syncthreads();
    }
    int ex = (t == 0) ? 0 : part[t - 1];
    for (int i = 0; i < CH; i++) {
        int idx = b + i;
        if (idx < N_DST) { row_start[idx] = ex; cursor[idx] = ex; ex += deg[idx]; }
    }
    if (t == 1023) row_start[N_DST] = part[1023];
}

__global__ void k_fill(const int* __restrict__ dst, const int* __restrict__ src,
                       int* __restrict__ cursor, int2* __restrict__ pk, int n) {
    int i = blockIdx.x * blockDim.x + threadIdx.x;
    if (i < n) {
        int p = atomicAdd(&cursor[dst[i]], 1);
        pk[p] = make_int2(i, src[i]);
    }
}

__global__ void k_mkrs2(const int* __restrict__ row_start, int2* __restrict__ rs2) {
    int i = blockIdx.x * blockDim.x + threadIdx.x;
    if (i < N_DST) rs2[i] = make_int2(row_start[i], row_start[i + 1]);
}

// ---------------- Aggregation: one wave per dst node ----------------
// Half-wave split gathers; hb rows are fp8 e4m3 (128B/row, 4B/lane) ->
// gather volume halved vs bf16, hb=6.4MB (better per-XCD L2 fit).
// Zero-reuse streams (pk, ef) stay NON-TEMPORAL.

__global__ __launch_bounds__(64) void k_agg(const int2* __restrict__ rs2,
                                            const int2* __restrict__ pk,
                                            const unsigned char* __restrict__ hb,
                                            const float* __restrict__ ef,
                                            ushort* __restrict__ hnb) {
    const int d = blockIdx.x;
    const int lane = threadIdx.x;
    const int ll = lane & 31;
    const int g = lane >> 5;
    const int2 se = rs2[d];
    const int start = se.x, end = se.y;
    const int deg = end - start;
    float a0 = 0.f, a1 = 0.f, a2 = 0.f, a3 = 0.f, ae = 0.f;
    const unsigned char* hbase = hb + 4 * ll;
    const float* ebase = ef + ll;

    for (int c = start; c < end; c += 64) {
        const int rem = end - c;
        const int m = rem < 64 ? rem : 64;
        int e = 0, s = 0;
        if (lane < m) {
            unsigned long long pv =
                __builtin_nontemporal_load((const unsigned long long*)&pk[c + lane]);
            e = (int)(unsigned)pv;
            s = (int)(unsigned)(pv >> 32);
        }
        int i = 0;
        for (; i + 16 <= m; i += 16) {
            unsigned u[8];
            float te[8];
#pragma unroll
            for (int j = 0; j < 8; j++) {
                const int sj = __shfl(s, i + 2 * j + g);
                u[j] = *(const unsigned*)(hbase + (size_t)sj * D_NEIGH);
            }
#pragma unroll
            for (int j = 0; j < 8; j++) {
                const int ee = __shfl(e, i + 2 * j + g);
                te[j] = __builtin_nontemporal_load(ebase + (size_t)ee * D_EDGE);
            }
#pragma unroll
            for (int j = 0; j < 8; j++) {
                float f[4];
                dec_fp8x4(u[j], f);
                a0 += f[0]; a1 += f[1]; a2 += f[2]; a3 += f[3];
                ae += te[j];
            }
        }
        for (; i + 8 <= m; i += 8) {
            unsigned u[4];
            float te[4];
#pragma unroll
            for (int j = 0; j < 4; j++) {
                const int sj = __shfl(s, i + 2 * j + g);
                u[j] = *(const unsigned*)(hbase + (size_t)sj * D_NEIGH);
            }
#pragma unroll
            for (int j = 0; j < 4; j++) {
                const int ee = __shfl(e, i + 2 * j + g);
                te[j] = __builtin_nontemporal_load(ebase + (size_t)ee * D_EDGE);
            }
#pragma unroll
            for (int j = 0; j < 4; j++) {
                float f[4];
                dec_fp8x4(u[j], f);
                a0 += f[0]; a1 += f[1]; a2 += f[2]; a3 += f[3];
                ae += te[j];
            }
        }
        for (; i < m; ++i) {   // tail singles: half-wave 0 only
            const int si = __builtin_amdgcn_readlane(s, i);
            const int ei = __builtin_amdgcn_readlane(e, i);
            if (g == 0) {
                const unsigned uu = *(const unsigned*)(hbase + (size_t)si * D_NEIGH);
                float f[4];
                dec_fp8x4(uu, f);
                a0 += f[0]; a1 += f[1]; a2 += f[2]; a3 += f[3];
                ae += __builtin_nontemporal_load(ebase + (size_t)ei * D_EDGE);
            }
        }
    }

    a0 += __shfl_xor(a0, 32); a1 += __shfl_xor(a1, 32);
    a2 += __shfl_xor(a2, 32); a3 += __shfl_xor(a3, 32);
    ae += __shfl_xor(ae, 32);

    if (lane < 32) {
        const float inv = 1.0f / (float)(deg > 0 ? deg : 1);
        ushort* o = hnb + (size_t)d * D_HN;
        *(ushort4*)(o + 4 * ll) = make_ushort4(f2bf(a0 * inv), f2bf(a1 * inv),
                                               f2bf(a2 * inv), f2bf(a3 * inv));
        o[128 + ll] = f2bf(ae * inv);
    }
}

// ---------------- Fused bf16-MFMA GEMM + ReLU + row-L2-norm ----------------
// 128 rows x 256 cols, 512 threads (8 waves 4x2). X: LDS double-buffered,
// one barrier per K-step. W: B-fragments from L2-resident Wb.

#define GBM 128

__global__ __launch_bounds__(512) void k_gemm_norm(const float* __restrict__ h_self,
                                                   const ushort* __restrict__ hnb,
                                                   const ushort* __restrict__ Wb,
                                                   float* __restrict__ out) {
    __shared__ __align__(16) ushort Xs[2][GBM * 40];
    __shared__ float rsum[2][GBM];
    __shared__ float invn[GBM];

    const int tid = threadIdx.x;
    const int lane = tid & 63;
    const int wid = tid >> 6;
    const int wm = wid >> 1;          // 0..3: row-group of 32
    const int wn = wid & 1;           // 0..1: col-group of 128
    const int brow = blockIdx.x * GBM;
    const int xrow = tid >> 2, xpart = tid & 3;   // stage: 8 bf16 per thread
    const int koff8 = lane >> 4, rsel = lane & 15;

    f32x4 acc[2][8] = {};

    auto stageX = [&](int t, int bufi) {
        const int k0 = t * 32;
        const int gr = brow + xrow;
        uv4 v0 = (uv4)0, v1 = (uv4)0;
        if (gr < N_DST) {
            if (k0 < 128) {
                const float* sp = h_self + (size_t)gr * D_SELF + k0 + xpart * 8;
                fv4 f0 = __builtin_nontemporal_load((const fv4*)(sp));
                fv4 f1 = __builtin_nontemporal_load((const fv4*)(sp + 4));
                v0 = (uv4){f2bf(f0.x), f2bf(f0.y), f2bf(f0.z), f2bf(f0.w)};
                v1 = (uv4){f2bf(f1.x), f2bf(f1.y), f2bf(f1.z), f2bf(f1.w)};
            } else {
                const ushort* sp = hnb + (size_t)gr * D_HN + (k0 - 128) + xpart * 8;
                v0 = __builtin_nontemporal_load((const uv4*)(sp));
                v1 = __builtin_nontemporal_load((const uv4*)(sp + 4));
            }
        }
        *(uv4*)&Xs[bufi][xrow * 40 + xpart * 8] = v0;
        *(uv4*)&Xs[bufi][xrow * 40 + xpart * 8 + 4] = v1;
    };

    stageX(0, 0);
    __syncthreads();

    for (int t = 0; t < 9; t++) {
        if (t < 8) stageX(t + 1, (t + 1) & 1);
        s16x8 af[2], bf[8];
#pragma unroll
        for (int fi = 0; fi < 2; fi++)
            af[fi] = *(const s16x8*)&Xs[t & 1][(wm * 32 + fi * 16 + rsel) * 40 + koff8 * 8];
#pragma unroll
        for (int fj = 0; fj < 8; fj++)
            bf[fj] = *(const s16x8*)&Wb[((size_t)(t * 4 + koff8) * 256 +
                                         (wn * 128 + fj * 16 + rsel)) * 8];
#pragma unroll
        for (int fi = 0; fi < 2; fi++)
#pragma unroll
            for (int fj = 0; fj < 8; fj++)
                acc[fi][fj] = __builtin_amdgcn_mfma_f32_16x16x32_bf16(af[fi], bf[fj], acc[fi][fj], 0, 0, 0);
        __syncthreads();
    }

    // relu + row sum-of-squares (C/D: col=lane&15, row=(lane>>4)*4+reg)
    float ss[2][4];
#pragma unroll
    for (int fi = 0; fi < 2; fi++)
#pragma unroll
        for (int j = 0; j < 4; j++) {
            float s = 0.f;
#pragma unroll
            for (int fj = 0; fj < 8; fj++) {
                float z = fmaxf(acc[fi][fj][j], 0.f);
                acc[fi][fj][j] = z;
                s += z * z;
            }
            ss[fi][j] = s;
        }
#pragma unroll
    for (int m = 1; m < 16; m <<= 1)
#pragma unroll
        for (int fi = 0; fi < 2; fi++)
#pragma unroll
            for (int j = 0; j < 4; j++) ss[fi][j] += __shfl_xor(ss[fi][j], m);
    if ((lane & 15) == 0) {
        const int gg = lane >> 4;
#pragma unroll
        for (int fi = 0; fi < 2; fi++)
#pragma unroll
            for (int j = 0; j < 4; j++)
                rsum[wn][wm * 32 + fi * 16 + gg * 4 + j] = ss[fi][j];
    }
    __syncthreads();
    if (tid < GBM) {
        float t = rsum[0][tid] + rsum[1][tid];
        invn[tid] = (t > 0.f) ? 1.f / sqrtf(t) : 1.f;
    }
    __syncthreads();

#pragma unroll
    for (int fi = 0; fi < 2; fi++)
#pragma unroll
        for (int j = 0; j < 4; j++) {
            const int rl = wm * 32 + fi * 16 + (lane >> 4) * 4 + j;
            const int row = brow + rl;
            if (row < N_DST) {
                const float iv = invn[rl];
#pragma unroll
                for (int fj = 0; fj < 8; fj++)
                    __builtin_nontemporal_store(acc[fi][fj][j] * iv,
                        &out[(size_t)row * D_OUT + wn * 128 + fj * 16 + (lane & 15)]);
            }
        }
}

// ---------------- launch ----------------

extern "C" void kernel_launch(void* const* d_in, const int* in_sizes, int n_in,
                              void* d_out, int out_size, void* d_ws, size_t ws_size,
                              hipStream_t stream) {
    const float* h_neigh = (const float*)d_in[0];
    const float* h_self  = (const float*)d_in[1];
    const float* ef      = (const float*)d_in[2];
    const int*   src     = (const int*)d_in[3];
    const int*   dst     = (const int*)d_in[4];
    const float* Wself   = (const float*)d_in[5];
    const float* Wneigh  = (const float*)d_in[6];
    float* out = (float*)d_out;

    char* ws = (char*)d_ws;
    const size_t PKB = (size_t)NB << CAPSH;           // 3,211,264 entries
    const size_t need_new = 524288ull + 2 * PKB * 8 + 12800000ull + 16000000ull + 147456ull; // ~81MB

    if (ws_size >= need_new) {
        int*   gcur0 = (int*)(ws + 0);                 // 196*16 ints (zeroed)
        int2*  rs2   = (int2*)(ws + 16384);            // 50000 int2
        int2*  pk1   = (int2*)(ws + 524288);           // 25.7MB
        int2*  pk2   = (int2*)(ws + 524288 + PKB * 8); // 25.7MB
        unsigned* hb = (unsigned*)(ws + 524288 + 2 * PKB * 8); // 6.4MB used (12.8 reserved)
        ushort* hnb  = (ushort*)((char*)hb + 12800000);        // 16MB
        ushort* Wb   = (ushort*)((char*)hnb + 16000000);       // 147KB

        hipMemsetAsync(gcur0, 0, NB * CPAD * sizeof(int), stream);
        k_pre<<<NSCAT1 + 6250 + 36, 256, 0, stream>>>(dst, src, gcur0, pk1,
                                                      h_neigh, hb, Wself, Wneigh, Wb);
        k_scat2<<<NB, 1024, 0, stream>>>(gcur0, pk1, pk2, rs2);
        k_agg<<<N_DST, 64, 0, stream>>>(rs2, pk2, (const unsigned char*)hb, ef, hnb);
        k_gemm_norm<<<(N_DST + GBM - 1) / GBM, 512, 0, stream>>>(h_self, hnb, Wb, out);
    } else {
        // fallback: simple CSR (needs ~43.4MB)
        int* deg       = (int*)(ws + 0);
        int* row_start = (int*)(ws + 262144);
        int* cursor    = (int*)(ws + 524288);
        int2* pk       = (int2*)(ws + 786432);            // ->13586432
        unsigned* hb   = (unsigned*)(ws + 13586432);      // 6.4MB used (12.8 reserved)
        ushort* hnb    = (ushort*)(ws + 26386432);        // ->42386432
        ushort* Wb     = (ushort*)(ws + 42386432);        // ->42533888
        int2* rs2      = (int2*)(ws + 42533888);          // ->42933888

        hipMemsetAsync(deg, 0, N_DST * sizeof(int), stream);
        k_cvtall<<<6286, 256, 0, stream>>>(h_neigh, hb, Wself, Wneigh, Wb);
        k_deg<<<(N_EDGES + 255) / 256, 256, 0, stream>>>(dst, deg, N_EDGES);
        k_scan<<<1, 1024, 0, stream>>>(deg, row_start, cursor);
        k_fill<<<(N_EDGES + 255) / 256, 256, 0, stream>>>(dst, src, cursor, pk, N_EDGES);
        k_mkrs2<<<(N_DST + 255) / 256, 256, 0, stream>>>(row_start, rs2);
        k_agg<<<N_DST, 64, 0, stream>>>(rs2, pk, (const unsigned char*)hb, ef, hnb);
        k_gemm_norm<<<(N_DST + GBM - 1) / GBM, 512, 0, stream>>>(h_self, hnb, Wb, out);
    }
}